// Round 1
// baseline (668.679 us; speedup 1.0000x reference)
//
#include <hip/hip_runtime.h>

typedef unsigned char  u8_t;
typedef unsigned short u16_t;
typedef unsigned int   u32_t;
typedef __attribute__((ext_vector_type(8))) short bf16x8;
typedef __attribute__((ext_vector_type(4))) float f32x4;

#define HW2  36864   // 192*192
#define NTOK 2304    // tokens per 48x48 window
#define NWIN 16

__device__ __forceinline__ u16_t f2bf(float f) {
    union { float f; u32_t u; } c; c.f = f;
    return (u16_t)((c.u + 0x7fffu + ((c.u >> 16) & 1u)) >> 16);   // RNE
}
__device__ __forceinline__ u32_t pk2(float a, float b) {
    return (u32_t)f2bf(a) | ((u32_t)f2bf(b) << 16);
}

// ---------------- projection: Q = x @ Wq^T + bq  (bf16, [win][tok][64]) ----------------
__global__ __launch_bounds__(256) void projq_kernel(
    const float* __restrict__ x, const float* __restrict__ ipw, const float* __restrict__ ipb,
    u16_t* __restrict__ Q)
{
    int lt = threadIdx.x & 127;
    int half = __builtin_amdgcn_readfirstlane(threadIdx.x >> 7);
    int t = blockIdx.x * 128 + lt;
    int win = t / NTOK, n = t % NTOK;
    int y = (win >> 2) * 48 + n / 48;
    int xx = (win & 3) * 48 + n % 48;
    int p = y * 192 + xx;

    float xv[64];
    #pragma unroll
    for (int c = 0; c < 64; ++c) xv[c] = x[c * HW2 + p];

    int dbase = half * 32;
    u32_t* qdst = (u32_t*)(Q + (size_t)t * 64 + dbase);
    for (int d2 = 0; d2 < 16; ++d2) {
        float aq[2];
        #pragma unroll
        for (int j = 0; j < 2; ++j) {
            int dd = dbase + d2 * 2 + j;
            const float* wq = ipw + dd * 64;
            float a = ipb[dd];
            #pragma unroll
            for (int c = 0; c < 64; ++c) a += xv[c] * wq[c];
            aq[j] = a;
        }
        qdst[d2] = pk2(aq[0], aq[1]);
    }
}

// ------- projection: K ([win][tok][64]) and V transposed ([win][ch][tok]), plus u_bin -------
__global__ __launch_bounds__(256) void projkv_kernel(
    const float* __restrict__ ref, const float* __restrict__ unc,
    const float* __restrict__ ipw, const float* __restrict__ ipb,
    u16_t* __restrict__ K, u16_t* __restrict__ Vt, u8_t* __restrict__ U8)
{
    int lt = threadIdx.x & 127;
    int half = __builtin_amdgcn_readfirstlane(threadIdx.x >> 7);
    int t = blockIdx.x * 128 + lt;
    int win = t / NTOK, n = t % NTOK;
    int y = (win >> 2) * 48 + n / 48;
    int xx = (win & 3) * 48 + n % 48;
    int p = y * 192 + xx;

    float rv[64];
    #pragma unroll
    for (int c = 0; c < 64; ++c) rv[c] = ref[c * HW2 + p];

    int dbase = half * 32;
    u32_t* kdst = (u32_t*)(K + (size_t)t * 64 + dbase);
    u16_t* vbase = Vt + (size_t)win * 64 * NTOK + n;
    for (int d2 = 0; d2 < 16; ++d2) {
        float ak[2], av[2];
        #pragma unroll
        for (int j = 0; j < 2; ++j) {
            int dd = dbase + d2 * 2 + j;
            const float* wk = ipw + (64 + dd) * 64;
            const float* wv = ipw + (128 + dd) * 64;
            float a = ipb[64 + dd], b = ipb[128 + dd];
            #pragma unroll
            for (int c = 0; c < 64; ++c) { a += rv[c] * wk[c]; b += rv[c] * wv[c]; }
            ak[j] = a; av[j] = b;
            vbase[(size_t)dd * NTOK] = f2bf(b);
        }
        kdst[d2] = pk2(ak[0], ak[1]);
    }
    if (half == 0) U8[t] = (unc[p] > 0.01f) ? 1 : 0;
}

// ------- mean_v[win][d] = mean(ref over window) @ Wv^T + bv  (certain-row uniform-attn result) -------
__global__ __launch_bounds__(256) void meanv_kernel(
    const float* __restrict__ ref, const float* __restrict__ ipw, const float* __restrict__ ipb,
    float* __restrict__ meanV)
{
    int win = blockIdx.x, tid = threadIdx.x;
    int c = tid & 63, q = tid >> 6;
    const float* base = ref + c * HW2 + (win >> 2) * 48 * 192 + (win & 3) * 48;
    float s = 0.f;
    for (int sy = q * 12; sy < q * 12 + 12; ++sy)
        for (int sx = 0; sx < 48; ++sx)
            s += base[sy * 192 + sx];
    __shared__ float part[64][4];
    __shared__ float mrs[64];
    part[c][q] = s;
    __syncthreads();
    if (tid < 64) mrs[tid] = (part[tid][0] + part[tid][1] + part[tid][2] + part[tid][3]) * (1.f / 2304.f);
    __syncthreads();
    if (tid < 64) {
        float a = ipb[128 + tid];
        const float* wv = ipw + (128 + tid) * 64;
        for (int cc = 0; cc < 64; ++cc) a += mrs[cc] * wv[cc];
        meanV[win * 64 + tid] = a;
    }
}

// ------- fold out_proj + w1:  Wc = W1*Wop,  bc = W1*bop + b1 -------
__global__ __launch_bounds__(256) void wcomb_kernel(
    const float* __restrict__ wop, const float* __restrict__ bop,
    const float* __restrict__ w1, const float* __restrict__ b1,
    float* __restrict__ Wc, float* __restrict__ bc)
{
    int tid = threadIdx.x;
    for (int idx = tid; idx < 4096; idx += 256) {
        int f = idx >> 6, d = idx & 63;
        float a = 0.f;
        for (int e = 0; e < 64; ++e) a += w1[f * 64 + e] * wop[e * 64 + d];
        Wc[idx] = a;
    }
    if (tid < 64) {
        float a = b1[tid];
        for (int e = 0; e < 64; ++e) a += w1[tid * 64 + e] * bop[e];
        bc[tid] = a;
    }
}

// ---------------- flash attention, swapped-operand MFMA form ----------------
// wave = 16 q-rows; S^T = mfma(Kfrag,Qfrag) so per-lane softmax state is for q-row (lane&15).
// O^T = mfma(Vt_frag, P^T_frag): accumulator cols are also q-row (lane&15) -> no redistribution.
__global__ __launch_bounds__(256, 2) void attn_kernel(
    const u16_t* __restrict__ Q, const u16_t* __restrict__ K, const u16_t* __restrict__ Vt,
    const u8_t* __restrict__ U8, const float* __restrict__ meanV,
    float* __restrict__ Oatt)
{
    const int lane = threadIdx.x & 63;
    const int wv = threadIdx.x >> 6;
    const int win = blockIdx.x / 36;
    const int rb = blockIdx.x % 36;
    const int lr = lane & 15;
    const int g = lane >> 4;
    const int row0 = rb * 64 + wv * 16;

    const u16_t* Qw = Q + (size_t)win * NTOK * 64;
    const u16_t* Kw = K + (size_t)win * NTOK * 64;
    const u16_t* Vw = Vt + (size_t)win * 64 * NTOK;
    const u8_t*  Uw = U8 + win * NTOK;

    // Q B-frags (held whole loop): lane -> q-row lr, k = g*8+i
    bf16x8 qf0 = *(const bf16x8*)(Qw + (size_t)(row0 + lr) * 64 + g * 8);
    bf16x8 qf1 = *(const bf16x8*)(Qw + (size_t)(row0 + lr) * 64 + 32 + g * 8);

    f32x4 ot0 = {0.f,0.f,0.f,0.f}, ot1 = ot0, ot2 = ot0, ot3 = ot0;
    float m = -__builtin_inff(), lsum = 0.f;
    const float SCL = 0.18033688011112043f;   // log2(e)/8

    __shared__ u16_t Plds[4][16][40];   // per-wave P tile [qrow][col], pad 40 (16B-aligned rows)

    for (int ct = 0; ct < 72; ++ct) {
        const int c0 = ct * 32;
        const u16_t* kb0 = Kw + (size_t)(c0 + lr) * 64 + g * 8;
        bf16x8 ka00 = *(const bf16x8*)(kb0);
        bf16x8 ka01 = *(const bf16x8*)(kb0 + 32);
        bf16x8 ka10 = *(const bf16x8*)(kb0 + 16 * 64);
        bf16x8 ka11 = *(const bf16x8*)(kb0 + 16 * 64 + 32);
        f32x4 s0 = {0.f,0.f,0.f,0.f}, s1 = {0.f,0.f,0.f,0.f};
        s0 = __builtin_amdgcn_mfma_f32_16x16x32_bf16(ka00, qf0, s0, 0, 0, 0);
        s0 = __builtin_amdgcn_mfma_f32_16x16x32_bf16(ka01, qf1, s0, 0, 0, 0);
        s1 = __builtin_amdgcn_mfma_f32_16x16x32_bf16(ka10, qf0, s1, 0, 0, 0);
        s1 = __builtin_amdgcn_mfma_f32_16x16x32_bf16(ka11, qf1, s1, 0, 0, 0);
        // lane holds S^T for q-row lr, col-tokens c0+4g+r (s0) and c0+16+4g+r (s1)
        u32_t u0 = *(const u32_t*)(Uw + c0 + 4 * g);
        u32_t u1 = *(const u32_t*)(Uw + c0 + 16 + 4 * g);
        float p[8];
        float mt = -__builtin_inff();
        #pragma unroll
        for (int r = 0; r < 4; ++r) {
            float v0 = ((u0 >> (8 * r)) & 0xffu) ? s0[r] * SCL : -__builtin_inff();
            float v1 = ((u1 >> (8 * r)) & 0xffu) ? s1[r] * SCL : -__builtin_inff();
            p[r] = v0; p[4 + r] = v1;
            mt = fmaxf(mt, fmaxf(v0, v1));
        }
        mt = fmaxf(mt, __shfl_xor(mt, 16));
        mt = fmaxf(mt, __shfl_xor(mt, 32));
        float mn = fmaxf(m, mt);
        float sf, ls = 0.f;
        if (mn == -__builtin_inff()) {          // row entirely masked so far
            sf = 1.f;
            #pragma unroll
            for (int i = 0; i < 8; ++i) p[i] = 0.f;
        } else {
            sf = __builtin_exp2f(m - mn);
            #pragma unroll
            for (int i = 0; i < 8; ++i) { p[i] = __builtin_exp2f(p[i] - mn); ls += p[i]; }
        }
        m = mn;
        ls += __shfl_xor(ls, 16);
        ls += __shfl_xor(ls, 32);
        lsum = lsum * sf + ls;
        ot0 *= sf; ot1 *= sf; ot2 *= sf; ot3 *= sf;

        // P -> LDS (row lr, cols 4g..4g+3 and 16+4g..16+4g+3), then b128 read as A^T-style frag
        u32_t* pw = (u32_t*)&Plds[wv][lr][4 * g];
        pw[0] = pk2(p[0], p[1]); pw[1] = pk2(p[2], p[3]);
        u32_t* pw2 = (u32_t*)&Plds[wv][lr][16 + 4 * g];
        pw2[0] = pk2(p[4], p[5]); pw2[1] = pk2(p[6], p[7]);

        bf16x8 pb = *(const bf16x8*)&Plds[wv][lr][g * 8];   // B-frag: n=q-row lr, k=col g*8+i

        const u16_t* vb = Vw + (size_t)lr * NTOK + c0 + g * 8;
        bf16x8 va0 = *(const bf16x8*)(vb);
        bf16x8 va1 = *(const bf16x8*)(vb + 16 * NTOK);
        bf16x8 va2 = *(const bf16x8*)(vb + 32 * NTOK);
        bf16x8 va3 = *(const bf16x8*)(vb + 48 * NTOK);
        ot0 = __builtin_amdgcn_mfma_f32_16x16x32_bf16(va0, pb, ot0, 0, 0, 0);
        ot1 = __builtin_amdgcn_mfma_f32_16x16x32_bf16(va1, pb, ot1, 0, 0, 0);
        ot2 = __builtin_amdgcn_mfma_f32_16x16x32_bf16(va2, pb, ot2, 0, 0, 0);
        ot3 = __builtin_amdgcn_mfma_f32_16x16x32_bf16(va3, pb, ot3, 0, 0, 0);
    }

    float linv = (lsum > 0.f) ? 1.f / lsum : 0.f;
    int urow = Uw[row0 + lr];
    float* orow = Oatt + ((size_t)(win * NTOK + row0 + lr)) * 64;
    const float* mv = meanV + win * 64;
    #pragma unroll
    for (int r = 0; r < 4; ++r) {
        int chb = 4 * g + r;   // O^T row m = ch within 16-block
        orow[chb]      = urow ? ot0[r] * linv : mv[chb];
        orow[16 + chb] = urow ? ot1[r] * linv : mv[16 + chb];
        orow[32 + chb] = urow ? ot2[r] * linv : mv[32 + chb];
        orow[48 + chb] = urow ? ot3[r] * linv : mv[48 + chb];
    }
}

// ------- refined[c][p] = x[c][p] + (o_att @ Wc^T + bc)[c]  (layout [C][H][W] for conv) -------
__global__ __launch_bounds__(256) void refined_kernel(
    const float* __restrict__ x, const float* __restrict__ Oatt,
    const float* __restrict__ Wc, const float* __restrict__ bc,
    float* __restrict__ refined)
{
    int lt = threadIdx.x & 127;
    int half = __builtin_amdgcn_readfirstlane(threadIdx.x >> 7);
    int t = blockIdx.x * 128 + lt;
    int win = t / NTOK, n = t % NTOK;
    int y = (win >> 2) * 48 + n / 48;
    int xx = (win & 3) * 48 + n % 48;
    int p = y * 192 + xx;

    float ov[64];
    const float4* o4 = (const float4*)(Oatt + (size_t)t * 64);
    #pragma unroll
    for (int i = 0; i < 16; ++i) {
        float4 v = o4[i];
        ov[4 * i] = v.x; ov[4 * i + 1] = v.y; ov[4 * i + 2] = v.z; ov[4 * i + 3] = v.w;
    }
    int dbase = half * 32;
    for (int d = 0; d < 32; ++d) {
        int dd = dbase + d;
        const float* wr = Wc + dd * 64;
        float a = bc[dd];
        #pragma unroll
        for (int e = 0; e < 64; ++e) a += ov[e] * wr[e];
        refined[dd * HW2 + p] = x[dd * HW2 + p] + a;
    }
}

// ------- conv3x3 + bias + relu -> out0; 1x1 -> out1; partition map -------
__global__ __launch_bounds__(256) void conv_kernel(
    const float* __restrict__ refined, const float* __restrict__ w3, const float* __restrict__ b3,
    const float* __restrict__ w4, const float* __restrict__ b4,
    float* __restrict__ out0, float* __restrict__ out1, float* __restrict__ pm)
{
    int tile = blockIdx.x;             // 96 y-tiles (2 rows) x 6 x-tiles (32 cols)
    int ty = tile / 6, tx = tile % 6;
    int y0 = ty * 2, x0 = tx * 32;
    int lt = threadIdx.x & 63;
    int oq = __builtin_amdgcn_readfirstlane(threadIdx.x >> 6);   // out-channel quarter
    int py = lt >> 5, px = lt & 31;
    int y = y0 + py, x = x0 + px;

    __shared__ float ti[4][36];        // rows y0-1..y0+2, cols x0-1..x0+32 (34 used)
    __shared__ float psum[4][64];

    float acc[16];
    #pragma unroll
    for (int o = 0; o < 16; ++o) acc[o] = 0.f;

    for (int ic = 0; ic < 64; ++ic) {
        __syncthreads();
        for (int i = threadIdx.x; i < 136; i += 256) {
            int r = i / 34, cc = i - r * 34;
            int yy = y0 - 1 + r, xxx = x0 - 1 + cc;
            float v = 0.f;
            if ((unsigned)yy < 192u && (unsigned)xxx < 192u) v = refined[ic * HW2 + yy * 192 + xxx];
            ti[r][cc] = v;
        }
        __syncthreads();
        float v00 = ti[py][px],     v01 = ti[py][px + 1],     v02 = ti[py][px + 2];
        float v10 = ti[py + 1][px], v11 = ti[py + 1][px + 1], v12 = ti[py + 1][px + 2];
        float v20 = ti[py + 2][px], v21 = ti[py + 2][px + 1], v22 = ti[py + 2][px + 2];
        const float* wb = w3 + ((size_t)(oq * 16) * 64 + ic) * 9;
        #pragma unroll 4
        for (int o = 0; o < 16; ++o) {
            const float* w = wb + (size_t)o * 576;
            acc[o] += v00 * w[0] + v01 * w[1] + v02 * w[2]
                    + v10 * w[3] + v11 * w[4] + v12 * w[5]
                    + v20 * w[6] + v21 * w[7] + v22 * w[8];
        }
    }
    int ob = oq * 16;
    float s4 = 0.f;
    #pragma unroll
    for (int o = 0; o < 16; ++o) {
        float r = fmaxf(acc[o] + b3[ob + o], 0.f);
        out0[(size_t)(ob + o) * HW2 + y * 192 + x] = r;
        s4 += r * w4[ob + o];
    }
    psum[oq][lt] = s4;
    __syncthreads();
    if (oq == 0) {
        out1[y * 192 + x] = psum[0][lt] + psum[1][lt] + psum[2][lt] + psum[3][lt] + b4[0];
        int ym = y % 48, xm = x % 48;
        bool border = (ym == 0) | (ym == 47) | (xm == 0) | (xm == 47);
        pm[y * 192 + x] = border ? 0.6f : 1.0f;
    }
}

extern "C" void kernel_launch(void* const* d_in, const int* in_sizes, int n_in,
                              void* d_out, int out_size, void* d_ws, size_t ws_size,
                              hipStream_t stream)
{
    const float* x   = (const float*)d_in[0];
    const float* ref = (const float*)d_in[1];
    const float* unc = (const float*)d_in[2];
    const float* ipw = (const float*)d_in[3];
    const float* ipb = (const float*)d_in[4];
    const float* opw = (const float*)d_in[5];
    const float* opb = (const float*)d_in[6];
    const float* w1  = (const float*)d_in[7];
    const float* b1  = (const float*)d_in[8];
    const float* w3  = (const float*)d_in[9];
    const float* b3  = (const float*)d_in[10];
    const float* w4  = (const float*)d_in[11];
    const float* b4  = (const float*)d_in[12];

    char* ws = (char*)d_ws;
    u16_t* Qb   = (u16_t*)(ws);                 // 4,718,592 B
    u16_t* Kb   = (u16_t*)(ws + 4718592);       // 4,718,592 B
    u16_t* Vtb  = (u16_t*)(ws + 9437184);       // 4,718,592 B
    u8_t*  U8p  = (u8_t*) (ws + 14155776);      // 36,864 B
    float* meanV   = (float*)(ws + 14192640);   // 4,096 B
    float* Wc      = (float*)(ws + 14196736);   // 16,384 B
    float* bc      = (float*)(ws + 14213120);   // 256 B
    float* Oatt    = (float*)(ws + 14213376);   // 9,437,184 B
    float* refined = (float*)(ws + 23650560);   // 9,437,184 B  (total 33,087,744 B)

    float* out0 = (float*)d_out;                // r3: [1,64,192,192]
    float* out1 = out0 + 2359296;               // out: [1,1,192,192]
    float* pmap = out0 + 2396160;               // partition_map

    projq_kernel <<<288, 256, 0, stream>>>(x, ipw, ipb, Qb);
    projkv_kernel<<<288, 256, 0, stream>>>(ref, unc, ipw, ipb, Kb, Vtb, U8p);
    meanv_kernel <<<16,  256, 0, stream>>>(ref, ipw, ipb, meanV);
    wcomb_kernel <<<1,   256, 0, stream>>>(opw, opb, w1, b1, Wc, bc);
    attn_kernel  <<<576, 256, 0, stream>>>(Qb, Kb, Vtb, U8p, meanV, Oatt);
    refined_kernel<<<288, 256, 0, stream>>>(x, Oatt, Wc, bc, refined);
    conv_kernel  <<<576, 256, 0, stream>>>(refined, w3, b3, w4, b4, out0, out1, pmap);
}

// Round 2
// 454.703 us; speedup vs baseline: 1.4706x; 1.4706x over previous
//
#include <hip/hip_runtime.h>

typedef unsigned char  u8_t;
typedef unsigned short u16_t;
typedef unsigned int   u32_t;
typedef __attribute__((ext_vector_type(8))) short bf16x8;
typedef __attribute__((ext_vector_type(4))) float f32x4;

#define HW2  36864   // 192*192
#define NTOK 2304    // tokens per 48x48 window

__device__ __forceinline__ u16_t f2bf(float f) {
    union { float f; u32_t u; } c; c.f = f;
    return (u16_t)((c.u + 0x7fffu + ((c.u >> 16) & 1u)) >> 16);   // RNE
}
__device__ __forceinline__ u32_t pk2(float a, float b) {
    return (u32_t)f2bf(a) | ((u32_t)f2bf(b) << 16);
}
__device__ __forceinline__ float bfhi(u32_t u) { union { u32_t u; float f; } c; c.u = u & 0xffff0000u; return c.f; }
__device__ __forceinline__ float bflo(u32_t u) { union { u32_t u; float f; } c; c.u = u << 16; return c.f; }

// ---------------- Q projection: bf16 [tok][64], LDS-transposed coalesced stores ----------------
__global__ __launch_bounds__(256) void projq_kernel(
    const float* __restrict__ x, const float* __restrict__ ipw, const float* __restrict__ ipb,
    u16_t* __restrict__ Q)
{
    __shared__ u32_t Qt[128][34];
    int lt = threadIdx.x & 127;
    int half = threadIdx.x >> 7;
    int t = blockIdx.x * 128 + lt;
    int win = t / NTOK, n = t % NTOK;
    int p = ((win >> 2) * 48 + n / 48) * 192 + (win & 3) * 48 + n % 48;

    float xv[64];
    #pragma unroll
    for (int c = 0; c < 64; ++c) xv[c] = x[c * HW2 + p];

    int dbase = half * 32;
    for (int d2 = 0; d2 < 16; ++d2) {
        float aq[2];
        #pragma unroll
        for (int j = 0; j < 2; ++j) {
            int dd = dbase + d2 * 2 + j;
            const float* wq = ipw + dd * 64;
            float a = ipb[dd];
            #pragma unroll
            for (int c = 0; c < 64; ++c) a += xv[c] * wq[c];
            aq[j] = a;
        }
        Qt[lt][half * 16 + d2] = pk2(aq[0], aq[1]);
    }
    __syncthreads();
    int tok = threadIdx.x >> 1, seg = (threadIdx.x & 1) * 16;
    u32_t* dst = (u32_t*)(Q + (size_t)(blockIdx.x * 128 + tok) * 64) + seg;
    #pragma unroll
    for (int j = 0; j < 16; ++j) dst[j] = Qt[tok][seg + j];
}

// ------- K ([tok][64]) + V transposed ([win][ch][tok]) + u_bin, coalesced via LDS -------
__global__ __launch_bounds__(256) void projkv_kernel(
    const float* __restrict__ ref, const float* __restrict__ unc,
    const float* __restrict__ ipw, const float* __restrict__ ipb,
    u16_t* __restrict__ K, u16_t* __restrict__ Vt, u8_t* __restrict__ U8)
{
    __shared__ u32_t Kt[128][34];
    __shared__ u16_t Vl[64][136];
    int lt = threadIdx.x & 127;
    int half = threadIdx.x >> 7;
    int t = blockIdx.x * 128 + lt;
    int win = t / NTOK, n = t % NTOK;
    int p = ((win >> 2) * 48 + n / 48) * 192 + (win & 3) * 48 + n % 48;

    float rv[64];
    #pragma unroll
    for (int c = 0; c < 64; ++c) rv[c] = ref[c * HW2 + p];

    int dbase = half * 32;
    for (int d2 = 0; d2 < 16; ++d2) {
        float ak[2], av[2];
        #pragma unroll
        for (int j = 0; j < 2; ++j) {
            int dd = dbase + d2 * 2 + j;
            const float* wk = ipw + (64 + dd) * 64;
            const float* wv = ipw + (128 + dd) * 64;
            float a = ipb[64 + dd], b = ipb[128 + dd];
            #pragma unroll
            for (int c = 0; c < 64; ++c) { a += rv[c] * wk[c]; b += rv[c] * wv[c]; }
            ak[j] = a; av[j] = b;
            Vl[dd][lt] = f2bf(b);
        }
        Kt[lt][half * 16 + d2] = pk2(ak[0], ak[1]);
    }
    if (half == 0) U8[t] = (unc[p] > 0.01f) ? 1 : 0;
    __syncthreads();
    // K store
    int tok = threadIdx.x >> 1, seg = (threadIdx.x & 1) * 16;
    u32_t* dst = (u32_t*)(K + (size_t)(blockIdx.x * 128 + tok) * 64) + seg;
    #pragma unroll
    for (int j = 0; j < 16; ++j) dst[j] = Kt[tok][seg + j];
    // V store: [win][ch][tok], 128-token stripe (blocks never straddle windows: 2304 = 18*128)
    int win0 = (blockIdx.x * 128) / NTOK, n0 = (blockIdx.x * 128) % NTOK;
    int ch = threadIdx.x >> 2, tc = (threadIdx.x & 3) * 32;
    const uint4* vsrc = (const uint4*)&Vl[ch][tc];
    uint4* vdst = (uint4*)(Vt + (size_t)win0 * 64 * NTOK + (size_t)ch * NTOK + n0 + tc);
    #pragma unroll
    for (int j = 0; j < 4; ++j) vdst[j] = vsrc[j];
}

// ------- per-window channel means of ref (stage 1) -------
__global__ __launch_bounds__(256) void meana_kernel(const float* __restrict__ ref, float* __restrict__ means)
{
    int win = blockIdx.x >> 2, cq = blockIdx.x & 3;
    int ch = cq * 16 + (threadIdx.x >> 4);
    int st = threadIdx.x & 15;
    const float* base = ref + (size_t)ch * HW2 + (win >> 2) * 48 * 192 + (win & 3) * 48;
    float s = 0.f;
    for (int yy = 0; yy < 48; ++yy) {
        const float* rp = base + yy * 192;
        s += rp[st] + rp[st + 16] + rp[st + 32];
    }
    __shared__ float red[16][17];
    red[threadIdx.x >> 4][st] = s;
    __syncthreads();
    if (threadIdx.x < 16) {
        float a = 0.f;
        #pragma unroll
        for (int k = 0; k < 16; ++k) a += red[threadIdx.x][k];
        means[win * 64 + cq * 16 + threadIdx.x] = a * (1.f / 2304.f);
    }
}

// ------- fold out_proj+w1 (Wc,bc) and meanV = means@Wv^T + bv -------
__global__ __launch_bounds__(256) void wcomb_kernel(
    const float* __restrict__ wop, const float* __restrict__ bop,
    const float* __restrict__ w1, const float* __restrict__ b1,
    const float* __restrict__ ipw, const float* __restrict__ ipb,
    const float* __restrict__ means,
    float* __restrict__ Wc, float* __restrict__ bc, float* __restrict__ meanV)
{
    int tid = threadIdx.x;
    for (int idx = tid; idx < 4096; idx += 256) {
        int f = idx >> 6, d = idx & 63;
        float a = 0.f;
        for (int e = 0; e < 64; ++e) a += w1[f * 64 + e] * wop[e * 64 + d];
        Wc[idx] = a;
    }
    if (tid < 64) {
        float a = b1[tid];
        for (int e = 0; e < 64; ++e) a += w1[tid * 64 + e] * bop[e];
        bc[tid] = a;
    }
    for (int o = tid; o < 1024; o += 256) {
        int win = o >> 6, d = o & 63;
        const float* mw = means + win * 64;
        const float* wv = ipw + (128 + d) * 64;
        float a = ipb[128 + d];
        for (int c = 0; c < 64; ++c) a += mw[c] * wv[c];
        meanV[o] = a;
    }
}

// ------- pack conv weights into MFMA A-frag order: [mf][ks][lane][8] bf16 -------
__global__ __launch_bounds__(256) void wpack_kernel(const float* __restrict__ w3, u16_t* __restrict__ Wpk)
{
    for (int idx = blockIdx.x * 256 + threadIdx.x; idx < 36864; idx += 36 * 256) {
        int i = idx & 7;
        int lane = (idx >> 3) & 63;
        int t2 = idx >> 9;            // mf*18 + ks
        int ks = t2 % 18, mf = t2 / 18;
        int oc = mf * 16 + (lane & 15);
        int g = lane >> 4;
        int tap = ks >> 1, icc = ks & 1;
        int dy = tap / 3, dx = tap - (tap / 3) * 3;
        int ic = icc * 32 + g * 8 + i;
        Wpk[idx] = f2bf(w3[(size_t)(oc * 64 + ic) * 9 + dy * 3 + dx]);
    }
}

// ---------------- flash attention: 4-wave in-block K-split, no-max exp2 softmax ----------------
__global__ __launch_bounds__(256) void attn_kernel(
    const u16_t* __restrict__ Q, const u16_t* __restrict__ K, const u16_t* __restrict__ Vt,
    const u8_t* __restrict__ U8, const float* __restrict__ meanV, u16_t* __restrict__ Oatt)
{
    __shared__ float Ored[4][16][68];
    __shared__ float Lred[4][16];
    __shared__ u16_t Plds[4][16][40];

    const int lane = threadIdx.x & 63;
    const int kq = threadIdx.x >> 6;
    const int lr = lane & 15;
    const int g  = lane >> 4;
    const int win = blockIdx.x / 144;
    const int rg  = blockIdx.x % 144;
    const int row0 = rg * 16;

    const u16_t* Qw = Q + (size_t)win * NTOK * 64;
    const u16_t* Kw = K + (size_t)win * NTOK * 64;
    const u16_t* Vw = Vt + (size_t)win * 64 * NTOK;
    const u8_t*  Uw = U8 + win * NTOK;

    bf16x8 qf0 = *(const bf16x8*)(Qw + (size_t)(row0 + lr) * 64 + g * 8);
    bf16x8 qf1 = *(const bf16x8*)(Qw + (size_t)(row0 + lr) * 64 + 32 + g * 8);

    f32x4 ot0 = {0.f,0.f,0.f,0.f}, ot1 = ot0, ot2 = ot0, ot3 = ot0;
    float lsum = 0.f;
    const float SCL = 0.18033688011112043f;   // log2(e)/8

    const int cbase = kq * 576;
    const u16_t* kp = Kw + (size_t)(cbase + lr) * 64 + g * 8;
    const u16_t* vp = Vw + (size_t)lr * NTOK + cbase + g * 8;

    bf16x8 kA0,kA1,kA2,kA3, kB0,kB1,kB2,kB3;
    #define LDK(d0,d1,d2,d3,off) { const u16_t* _b = kp + (off); d0 = *(const bf16x8*)_b; d1 = *(const bf16x8*)(_b+32); d2 = *(const bf16x8*)(_b+1024); d3 = *(const bf16x8*)(_b+1024+32); }
    LDK(kA0,kA1,kA2,kA3, 0)

    auto body = [&](bf16x8 k0, bf16x8 k1, bf16x8 k2, bf16x8 k3, int t) {
        const int c0 = cbase + t * 32;
        f32x4 s0 = {0.f,0.f,0.f,0.f}, s1 = {0.f,0.f,0.f,0.f};
        s0 = __builtin_amdgcn_mfma_f32_16x16x32_bf16(k0, qf0, s0, 0, 0, 0);
        s0 = __builtin_amdgcn_mfma_f32_16x16x32_bf16(k1, qf1, s0, 0, 0, 0);
        s1 = __builtin_amdgcn_mfma_f32_16x16x32_bf16(k2, qf0, s1, 0, 0, 0);
        s1 = __builtin_amdgcn_mfma_f32_16x16x32_bf16(k3, qf1, s1, 0, 0, 0);
        u32_t u0 = *(const u32_t*)(Uw + c0 + 4 * g);
        u32_t u1 = *(const u32_t*)(Uw + c0 + 16 + 4 * g);
        float p[8]; float ls = 0.f;
        #pragma unroll
        for (int r = 0; r < 4; ++r) {
            float e0 = __builtin_exp2f(s0[r] * SCL);
            float e1 = __builtin_exp2f(s1[r] * SCL);
            p[r]     = ((u0 >> (8 * r)) & 0xffu) ? e0 : 0.f;
            p[4 + r] = ((u1 >> (8 * r)) & 0xffu) ? e1 : 0.f;
            ls += p[r] + p[4 + r];
        }
        ls += __shfl_xor(ls, 16);
        ls += __shfl_xor(ls, 32);
        lsum += ls;
        u32_t* pw = (u32_t*)&Plds[kq][lr][4 * g];
        pw[0] = pk2(p[0], p[1]); pw[1] = pk2(p[2], p[3]);
        u32_t* pw2 = (u32_t*)&Plds[kq][lr][16 + 4 * g];
        pw2[0] = pk2(p[4], p[5]); pw2[1] = pk2(p[6], p[7]);
        bf16x8 pb = *(const bf16x8*)&Plds[kq][lr][g * 8];
        const u16_t* vb = vp + t * 32;
        bf16x8 va0 = *(const bf16x8*)(vb);
        bf16x8 va1 = *(const bf16x8*)(vb + 16 * NTOK);
        bf16x8 va2 = *(const bf16x8*)(vb + 32 * NTOK);
        bf16x8 va3 = *(const bf16x8*)(vb + 48 * NTOK);
        ot0 = __builtin_amdgcn_mfma_f32_16x16x32_bf16(va0, pb, ot0, 0, 0, 0);
        ot1 = __builtin_amdgcn_mfma_f32_16x16x32_bf16(va1, pb, ot1, 0, 0, 0);
        ot2 = __builtin_amdgcn_mfma_f32_16x16x32_bf16(va2, pb, ot2, 0, 0, 0);
        ot3 = __builtin_amdgcn_mfma_f32_16x16x32_bf16(va3, pb, ot3, 0, 0, 0);
    };

    #pragma unroll 1
    for (int tt = 0; tt < 9; ++tt) {
        LDK(kB0,kB1,kB2,kB3, (size_t)(2 * tt + 1) * 2048)
        body(kA0, kA1, kA2, kA3, 2 * tt);
        if (tt < 8) LDK(kA0,kA1,kA2,kA3, (size_t)(2 * tt + 2) * 2048)
        body(kB0, kB1, kB2, kB3, 2 * tt + 1);
    }

    if (g == 0) Lred[kq][lr] = lsum;
    #pragma unroll
    for (int r = 0; r < 4; ++r) {
        Ored[kq][lr][4 * g + r]      = ot0[r];
        Ored[kq][lr][16 + 4 * g + r] = ot1[r];
        Ored[kq][lr][32 + 4 * g + r] = ot2[r];
        Ored[kq][lr][48 + 4 * g + r] = ot3[r];
    }
    __syncthreads();

    int qr = threadIdx.x >> 4;
    int c4 = (threadIdx.x & 15) * 4;
    float l = Lred[0][qr] + Lred[1][qr] + Lred[2][qr] + Lred[3][qr];
    float o0 = Ored[0][qr][c4+0] + Ored[1][qr][c4+0] + Ored[2][qr][c4+0] + Ored[3][qr][c4+0];
    float o1 = Ored[0][qr][c4+1] + Ored[1][qr][c4+1] + Ored[2][qr][c4+1] + Ored[3][qr][c4+1];
    float o2 = Ored[0][qr][c4+2] + Ored[1][qr][c4+2] + Ored[2][qr][c4+2] + Ored[3][qr][c4+2];
    float o3 = Ored[0][qr][c4+3] + Ored[1][qr][c4+3] + Ored[2][qr][c4+3] + Ored[3][qr][c4+3];
    float linv = (l > 0.f) ? 1.f / l : 0.f;
    int gt = win * NTOK + row0 + qr;
    u32_t w0, w1;
    if (Uw[row0 + qr]) { w0 = pk2(o0 * linv, o1 * linv); w1 = pk2(o2 * linv, o3 * linv); }
    else { const float* mv = meanV + win * 64 + c4; w0 = pk2(mv[0], mv[1]); w1 = pk2(mv[2], mv[3]); }
    u32_t* od = (u32_t*)(Oatt + (size_t)gt * 64) + (threadIdx.x & 15) * 2;
    od[0] = w0; od[1] = w1;
}

// ------- refined(bf16 [C][H][W]) = x + Oatt @ Wc^T + bc -------
__global__ __launch_bounds__(256) void refined_kernel(
    const float* __restrict__ x, const u16_t* __restrict__ Oatt,
    const float* __restrict__ Wc, const float* __restrict__ bc,
    u16_t* __restrict__ refined)
{
    int lt = threadIdx.x & 127;
    int half = threadIdx.x >> 7;
    int t = blockIdx.x * 128 + lt;
    int win = t / NTOK, n = t % NTOK;
    int p = ((win >> 2) * 48 + n / 48) * 192 + (win & 3) * 48 + n % 48;

    float ov[64];
    const uint2* o2 = (const uint2*)(Oatt + (size_t)t * 64);
    #pragma unroll
    for (int i = 0; i < 16; ++i) {
        uint2 v = o2[i];
        ov[4*i]   = bflo(v.x); ov[4*i+1] = bfhi(v.x);
        ov[4*i+2] = bflo(v.y); ov[4*i+3] = bfhi(v.y);
    }
    int dbase = half * 32;
    for (int d = 0; d < 32; ++d) {
        int dd = dbase + d;
        const float* wr = Wc + dd * 64;
        float a = bc[dd];
        #pragma unroll
        for (int e = 0; e < 64; ++e) a += ov[e] * wr[e];
        refined[(size_t)dd * HW2 + p] = f2bf(x[(size_t)dd * HW2 + p] + a);
    }
}

// ------- conv3x3(+bias,relu)->out0, 1x1->out1, partition map; implicit-GEMM MFMA -------
__global__ __launch_bounds__(256) void conv_kernel(
    const u16_t* __restrict__ refined, const u16_t* __restrict__ Wpk,
    const float* __restrict__ b3, const float* __restrict__ w4, const float* __restrict__ b4,
    float* __restrict__ out0, float* __restrict__ out1, float* __restrict__ pm)
{
    __shared__ u16_t tile[3 * 98 * 64];    // [r][cc][ic], slot-swizzled; 37,632 B
    __shared__ float ps[96];
    const int y  = blockIdx.x >> 1;
    const int xh = (blockIdx.x & 1) * 96;
    const int tid = threadIdx.x;
    if (tid < 96) ps[tid] = 0.f;

    for (int idx = tid; idx < 2352; idx += 256) {     // 3 rows * 8 chunks * 98 cols
        int r = idx / 784; int rem = idx - r * 784;
        int tg = rem / 98; int cc = rem - tg * 98;
        int yy = y - 1 + r; int xg = xh + cc - 1;
        bf16x8 val = {0,0,0,0,0,0,0,0};
        if ((unsigned)yy < 192u && (unsigned)xg < 192u) {
            const u16_t* src = refined + (size_t)(tg * 8) * HW2 + yy * 192 + xg;
            #pragma unroll
            for (int i = 0; i < 8; ++i) val[i] = (short)src[(size_t)i * HW2];
        }
        int slot = (tg + cc) & 7;
        *(bf16x8*)((char*)tile + (size_t)(r * 98 + cc) * 128 + slot * 16) = val;
    }
    __syncthreads();

    const int lane = tid & 63, mf = tid >> 6;
    const int ln = lane & 15, g = lane >> 4;

    bf16x8 wf[18];
    #pragma unroll
    for (int ks = 0; ks < 18; ++ks)
        wf[ks] = *(const bf16x8*)(Wpk + (size_t)((mf * 18 + ks) * 64 + lane) * 8);

    float b3v[4], w4v[4];
    #pragma unroll
    for (int r = 0; r < 4; ++r) { int oc = mf * 16 + 4 * g + r; b3v[r] = b3[oc]; w4v[r] = w4[oc]; }

    for (int nf = 0; nf < 6; ++nf) {
        int xl = nf * 16 + ln;
        f32x4 acc0 = {0.f,0.f,0.f,0.f}, acc1 = acc0;
        #pragma unroll
        for (int ks = 0; ks < 18; ++ks) {
            int tap = ks >> 1, icc = ks & 1;
            int dy = tap / 3, dx = tap - (tap / 3) * 3;
            int cc = xl + dx;
            int slot = (icc * 4 + g + cc) & 7;
            bf16x8 bfr = *(const bf16x8*)((const char*)tile + (size_t)(dy * 98 + cc) * 128 + slot * 16);
            if (ks & 1) acc1 = __builtin_amdgcn_mfma_f32_16x16x32_bf16(wf[ks], bfr, acc1, 0, 0, 0);
            else        acc0 = __builtin_amdgcn_mfma_f32_16x16x32_bf16(wf[ks], bfr, acc0, 0, 0, 0);
        }
        int xg = xh + xl;
        float s4 = 0.f;
        #pragma unroll
        for (int r = 0; r < 4; ++r) {
            int oc = mf * 16 + 4 * g + r;
            float v = fmaxf(acc0[r] + acc1[r] + b3v[r], 0.f);
            out0[(size_t)oc * HW2 + y * 192 + xg] = v;
            s4 += v * w4v[r];
        }
        atomicAdd(&ps[xl], s4);
    }
    __syncthreads();
    if (tid < 96) {
        int xg = xh + tid;
        out1[y * 192 + xg] = ps[tid] + b4[0];
        int ym = y % 48, xm = xg % 48;
        pm[y * 192 + xg] = ((ym == 0) | (ym == 47) | (xm == 0) | (xm == 47)) ? 0.6f : 1.0f;
    }
}

extern "C" void kernel_launch(void* const* d_in, const int* in_sizes, int n_in,
                              void* d_out, int out_size, void* d_ws, size_t ws_size,
                              hipStream_t stream)
{
    const float* x   = (const float*)d_in[0];
    const float* ref = (const float*)d_in[1];
    const float* unc = (const float*)d_in[2];
    const float* ipw = (const float*)d_in[3];
    const float* ipb = (const float*)d_in[4];
    const float* opw = (const float*)d_in[5];
    const float* opb = (const float*)d_in[6];
    const float* w1  = (const float*)d_in[7];
    const float* b1  = (const float*)d_in[8];
    const float* w3  = (const float*)d_in[9];
    const float* b3  = (const float*)d_in[10];
    const float* w4  = (const float*)d_in[11];
    const float* b4  = (const float*)d_in[12];

    char* ws = (char*)d_ws;
    u16_t* Qb    = (u16_t*)(ws);                  // 4,718,592
    u16_t* Kb    = (u16_t*)(ws + 4718592);        // 4,718,592
    u16_t* Vtb   = (u16_t*)(ws + 9437184);        // 4,718,592
    u8_t*  U8p   = (u8_t*) (ws + 14155776);       // 36,864
    float* means = (float*)(ws + 14192640);       // 4,096
    float* meanV = (float*)(ws + 14196736);       // 4,096
    float* Wc    = (float*)(ws + 14200832);       // 16,384
    float* bc    = (float*)(ws + 14217216);       // 256
    u16_t* Wpk   = (u16_t*)(ws + 14217472);       // 73,728
    u16_t* Oatt  = (u16_t*)(ws + 14291200);       // 4,718,592
    u16_t* refd  = (u16_t*)(ws + 19009792);       // 4,718,592  (total 23,728,384 B)

    float* out0 = (float*)d_out;                  // r3: [1,64,192,192]
    float* out1 = out0 + 2359296;                 // out: [1,1,192,192]
    float* pmap = out0 + 2396160;                 // partition_map

    projq_kernel  <<<288, 256, 0, stream>>>(x, ipw, ipb, Qb);
    projkv_kernel <<<288, 256, 0, stream>>>(ref, unc, ipw, ipb, Kb, Vtb, U8p);
    meana_kernel  <<<64,  256, 0, stream>>>(ref, means);
    wcomb_kernel  <<<1,   256, 0, stream>>>(opw, opb, w1, b1, ipw, ipb, means, Wc, bc, meanV);
    wpack_kernel  <<<36,  256, 0, stream>>>(w3, Wpk);
    attn_kernel   <<<2304, 256, 0, stream>>>(Qb, Kb, Vtb, U8p, meanV, Oatt);
    refined_kernel<<<288, 256, 0, stream>>>(x, Oatt, Wc, bc, refd);
    conv_kernel   <<<384, 256, 0, stream>>>(refd, Wpk, b3, w4, b4, out0, out1, pmap);
}

// Round 3
// 345.794 us; speedup vs baseline: 1.9337x; 1.3150x over previous
//
#include <hip/hip_runtime.h>
#include <hip/hip_bf16.h>

typedef unsigned char  u8_t;
typedef unsigned short u16_t;
typedef unsigned int   u32_t;
typedef __attribute__((ext_vector_type(8))) short bf16x8;
typedef __attribute__((ext_vector_type(4))) float f32x4;
typedef __attribute__((ext_vector_type(16))) float f32x16;

#define HW2  36864   // 192*192
#define NTOK 2304    // tokens per 48x48 window

__device__ __forceinline__ u32_t cvtpk(float a, float b) {
    union { __hip_bfloat162 h; u32_t u; } c;
    c.h = __float22bfloat162_rn(float2{a, b});
    return c.u;
}
__device__ __forceinline__ float bfhi(u32_t u) { union { u32_t u; float f; } c; c.u = u & 0xffff0000u; return c.f; }
__device__ __forceinline__ float bflo(u32_t u) { union { u32_t u; float f; } c; c.u = u << 16; return c.f; }

union U8x { u32_t u[4]; bf16x8 v; };

// ---------------- Q projection: bf16 [tok][64], scale log2(e)/8 folded in ----------------
__global__ __launch_bounds__(256) void projq_kernel(
    const float* __restrict__ x, const float* __restrict__ ipw, const float* __restrict__ ipb,
    u16_t* __restrict__ Q)
{
    __shared__ u32_t Qt[128][34];
    const float SCL = 0.18033688011112043f;   // log2(e)/8
    int bid = (blockIdx.x & 7) * 36 + (blockIdx.x >> 3);
    int lt = threadIdx.x & 127;
    int half = threadIdx.x >> 7;
    int t = bid * 128 + lt;
    int win = t / NTOK, n = t % NTOK;
    int p = ((win >> 2) * 48 + n / 48) * 192 + (win & 3) * 48 + n % 48;

    float xv[64];
    #pragma unroll
    for (int c = 0; c < 64; ++c) xv[c] = x[c * HW2 + p];

    int dbase = half * 32;
    for (int d2 = 0; d2 < 16; ++d2) {
        float aq[2];
        #pragma unroll
        for (int j = 0; j < 2; ++j) {
            int dd = dbase + d2 * 2 + j;
            const float* wq = ipw + dd * 64;
            float a = ipb[dd];
            #pragma unroll
            for (int c = 0; c < 64; ++c) a += xv[c] * wq[c];
            aq[j] = a * SCL;
        }
        Qt[lt][half * 16 + d2] = cvtpk(aq[0], aq[1]);
    }
    __syncthreads();
    int tok = threadIdx.x >> 1, seg = (threadIdx.x & 1) * 16;
    u32_t* dst = (u32_t*)(Q + (size_t)(bid * 128 + tok) * 64) + seg;
    #pragma unroll
    for (int j = 0; j < 16; ++j) dst[j] = Qt[tok][seg + j];
}

// ------- K ([tok][64]) + V transposed+token-permuted ([win][ch][pos]) + float mask -------
__global__ __launch_bounds__(256) void projkv_kernel(
    const float* __restrict__ ref, const float* __restrict__ unc,
    const float* __restrict__ ipw, const float* __restrict__ ipb,
    u16_t* __restrict__ K, u16_t* __restrict__ Vt, float* __restrict__ Uf)
{
    __shared__ u32_t Kt[128][34];
    __shared__ u16_t Vl[64][136];
    int bid = (blockIdx.x & 7) * 36 + (blockIdx.x >> 3);
    int lt = threadIdx.x & 127;
    int half = threadIdx.x >> 7;
    int t = bid * 128 + lt;
    int win = t / NTOK, n = t % NTOK;
    int p = ((win >> 2) * 48 + n / 48) * 192 + (win & 3) * 48 + n % 48;

    // token-permute for MFMA B-frag order: swap 4-token sub-blocks 1<->2 and 5<->6 per 32
    int sub = (lt >> 2) & 7;
    int plt = (((sub ^ (sub >> 1)) & 1) ? (lt ^ 12) : lt);

    float rv[64];
    #pragma unroll
    for (int c = 0; c < 64; ++c) rv[c] = ref[c * HW2 + p];

    int dbase = half * 32;
    for (int d2 = 0; d2 < 16; ++d2) {
        float ak[2];
        #pragma unroll
        for (int j = 0; j < 2; ++j) {
            int dd = dbase + d2 * 2 + j;
            const float* wk = ipw + (64 + dd) * 64;
            const float* wv = ipw + (128 + dd) * 64;
            float a = ipb[64 + dd], b = ipb[128 + dd];
            #pragma unroll
            for (int c = 0; c < 64; ++c) { a += rv[c] * wk[c]; b += rv[c] * wv[c]; }
            ak[j] = a;
            Vl[dd][plt] = (u16_t)(cvtpk(b, 0.f) & 0xffffu);
        }
        Kt[lt][half * 16 + d2] = cvtpk(ak[0], ak[1]);
    }
    if (half == 0) Uf[t] = (unc[p] > 0.01f) ? 1.f : 0.f;
    __syncthreads();
    int tok = threadIdx.x >> 1, seg = (threadIdx.x & 1) * 16;
    u32_t* dst = (u32_t*)(K + (size_t)(bid * 128 + tok) * 64) + seg;
    #pragma unroll
    for (int j = 0; j < 16; ++j) dst[j] = Kt[tok][seg + j];
    int win0 = (bid * 128) / NTOK, n0 = (bid * 128) % NTOK;
    int ch = threadIdx.x >> 2, tc = (threadIdx.x & 3) * 32;
    const uint4* vsrc = (const uint4*)&Vl[ch][tc];
    uint4* vdst = (uint4*)(Vt + (size_t)win0 * 64 * NTOK + (size_t)ch * NTOK + n0 + tc);
    #pragma unroll
    for (int j = 0; j < 4; ++j) vdst[j] = vsrc[j];
}

// ------- meanV[win][ch] = mean over tokens of V (linearity of certain-row uniform attn) -------
__global__ __launch_bounds__(256) void meanv_kernel(const u16_t* __restrict__ Vt, float* __restrict__ meanV)
{
    int win = blockIdx.x;
    int ch = threadIdx.x >> 2, qp = threadIdx.x & 3;
    const uint2* src = (const uint2*)(Vt + (size_t)win * 64 * NTOK + (size_t)ch * NTOK + qp * 576);
    float s = 0.f;
    for (int i = 0; i < 144; ++i) {
        uint2 v = src[i];
        s += bflo(v.x) + bfhi(v.x) + bflo(v.y) + bfhi(v.y);
    }
    __shared__ float red[64][4];
    red[ch][qp] = s;
    __syncthreads();
    if (threadIdx.x < 64) {
        meanV[win * 64 + threadIdx.x] =
            (red[threadIdx.x][0] + red[threadIdx.x][1] + red[threadIdx.x][2] + red[threadIdx.x][3]) * (1.f / 2304.f);
    }
}

// ------- prep: block 0 folds out_proj+w1 -> (Wc,bc); blocks 1..36 pack conv weights -------
__global__ __launch_bounds__(256) void prep_kernel(
    const float* __restrict__ wop, const float* __restrict__ bop,
    const float* __restrict__ w1, const float* __restrict__ b1,
    const float* __restrict__ w3,
    float* __restrict__ Wc, float* __restrict__ bc, u16_t* __restrict__ Wpk)
{
    int tid = threadIdx.x;
    if (blockIdx.x == 0) {
        for (int idx = tid; idx < 4096; idx += 256) {
            int f = idx >> 6, d = idx & 63;
            float a = 0.f;
            for (int e = 0; e < 64; ++e) a += w1[f * 64 + e] * wop[e * 64 + d];
            Wc[idx] = a;
        }
        if (tid < 64) {
            float a = b1[tid];
            for (int e = 0; e < 64; ++e) a += w1[tid * 64 + e] * bop[e];
            bc[tid] = a;
        }
    } else {
        for (int idx = (blockIdx.x - 1) * 256 + tid; idx < 36864; idx += 9216) {
            int i = idx & 7;
            int lane = (idx >> 3) & 63;
            int t2 = idx >> 9;
            int ks = t2 % 18, mf = t2 / 18;
            int oc = mf * 16 + (lane & 15);
            int g = lane >> 4;
            int tap = ks >> 1, icc = ks & 1;
            int dy = tap / 3, dx = tap - (tap / 3) * 3;
            int ic = icc * 32 + g * 8 + i;
            Wpk[idx] = (u16_t)(cvtpk(w3[(size_t)(oc * 64 + ic) * 9 + dy * 3 + dx], 0.f) & 0xffffu);
        }
    }
}

// ---------------- attention: 32x32 MFMA, in-register P, split-K x4, 64 q-rows/wave ----------------
__global__ __launch_bounds__(256) void attn_kernel(
    const u16_t* __restrict__ Q, const u16_t* __restrict__ K, const u16_t* __restrict__ Vt,
    const float* __restrict__ Uf, const float* __restrict__ meanV, u16_t* __restrict__ Oatt)
{
    __shared__ float Ored[4][32][68];
    __shared__ float Lred2[2][4][32];

    const int bid = (blockIdx.x & 7) * 72 + (blockIdx.x >> 3);   // XCD-bijective swizzle (576%8==0)
    const int lane = threadIdx.x & 63;
    const int kq = threadIdx.x >> 6;
    const int q  = lane & 31;
    const int hi = lane >> 5;
    const int win = bid / 36;
    const int rg  = bid % 36;
    const int row0 = rg * 64;

    const u16_t* Qw = Q + (size_t)win * NTOK * 64;
    const u16_t* Kw = K + (size_t)win * NTOK * 64;
    const u16_t* Vw = Vt + (size_t)win * 64 * NTOK;
    const float* Uw = Uf + win * NTOK;

    bf16x8 qb0[4], qb1[4];
    #pragma unroll
    for (int s = 0; s < 4; ++s) {
        qb0[s] = *(const bf16x8*)(Qw + (size_t)(row0 + q) * 64 + s * 16 + hi * 8);
        qb1[s] = *(const bf16x8*)(Qw + (size_t)(row0 + 32 + q) * 64 + s * 16 + hi * 8);
    }

    const f32x16 Z16 = {0.f,0.f,0.f,0.f,0.f,0.f,0.f,0.f,0.f,0.f,0.f,0.f,0.f,0.f,0.f,0.f};
    f32x16 acc00 = Z16, acc01 = Z16, acc10 = Z16, acc11 = Z16;
    float lsum0 = 0.f, lsum1 = 0.f;

    const u16_t* kp = Kw + (size_t)q * 64 + hi * 8;
    const u16_t* vp = Vw + (size_t)q * NTOK + hi * 8;
    const float* up = Uw + 4 * hi;

#define MF32(A, B, C) __builtin_amdgcn_mfma_f32_32x32x16_bf16(A, B, C, 0, 0, 0)

    #pragma unroll 1
    for (int ct = 0; ct < 18; ++ct) {
        const int c0 = kq * 576 + ct * 32;
        bf16x8 ka0 = *(const bf16x8*)(kp + (size_t)c0 * 64);
        bf16x8 ka1 = *(const bf16x8*)(kp + (size_t)c0 * 64 + 16);
        bf16x8 ka2 = *(const bf16x8*)(kp + (size_t)c0 * 64 + 32);
        bf16x8 ka3 = *(const bf16x8*)(kp + (size_t)c0 * 64 + 48);
        bf16x8 va00 = *(const bf16x8*)(vp + c0);
        bf16x8 va01 = *(const bf16x8*)(vp + c0 + 16);
        bf16x8 va10 = *(const bf16x8*)(vp + 32 * NTOK + c0);
        bf16x8 va11 = *(const bf16x8*)(vp + 32 * NTOK + c0 + 16);
        float mfv[16];
        *(float4*)&mfv[0]  = *(const float4*)(up + c0);
        *(float4*)&mfv[4]  = *(const float4*)(up + c0 + 8);
        *(float4*)&mfv[8]  = *(const float4*)(up + c0 + 16);
        *(float4*)&mfv[12] = *(const float4*)(up + c0 + 24);

#define QS_TILE(QB, ACC0, ACC1, LSUM) {                                          \
        f32x16 s = Z16;                                                          \
        s = MF32(ka0, QB[0], s); s = MF32(ka1, QB[1], s);                        \
        s = MF32(ka2, QB[2], s); s = MF32(ka3, QB[3], s);                        \
        float pv[16]; float lls = 0.f;                                           \
        _Pragma("unroll") for (int r = 0; r < 16; ++r) {                         \
            pv[r] = __builtin_exp2f(s[r]) * mfv[r]; lls += pv[r];                \
        }                                                                        \
        LSUM += lls;                                                             \
        U8x f0, f1;                                                              \
        _Pragma("unroll") for (int j = 0; j < 4; ++j) {                          \
            f0.u[j] = cvtpk(pv[2 * j], pv[2 * j + 1]);                           \
            f1.u[j] = cvtpk(pv[8 + 2 * j], pv[8 + 2 * j + 1]);                   \
        }                                                                        \
        ACC0 = MF32(va00, f0.v, ACC0); ACC0 = MF32(va01, f1.v, ACC0);            \
        ACC1 = MF32(va10, f0.v, ACC1); ACC1 = MF32(va11, f1.v, ACC1); }

        QS_TILE(qb0, acc00, acc01, lsum0)
        QS_TILE(qb1, acc10, acc11, lsum1)
#undef QS_TILE
    }

    float l0 = lsum0 + __shfl_xor(lsum0, 32);
    float l1 = lsum1 + __shfl_xor(lsum1, 32);
    if (hi == 0) { Lred2[0][kq][q] = l0; Lred2[1][kq][q] = l1; }

    const int qr = threadIdx.x >> 3;
    const int ch0 = (threadIdx.x & 7) * 8;

    #pragma unroll
    for (int qs = 0; qs < 2; ++qs) {
        f32x16 a0 = qs ? acc10 : acc00;
        f32x16 a1 = qs ? acc11 : acc01;
        #pragma unroll
        for (int rr = 0; rr < 4; ++rr) {
            float4 v0 = { a0[4*rr], a0[4*rr+1], a0[4*rr+2], a0[4*rr+3] };
            float4 v1 = { a1[4*rr], a1[4*rr+1], a1[4*rr+2], a1[4*rr+3] };
            *(float4*)&Ored[kq][q][8 * rr + 4 * hi]      = v0;
            *(float4*)&Ored[kq][q][32 + 8 * rr + 4 * hi] = v1;
        }
        __syncthreads();
        float o[8] = {0.f,0.f,0.f,0.f,0.f,0.f,0.f,0.f};
        #pragma unroll
        for (int w = 0; w < 4; ++w) {
            float4 a = *(float4*)&Ored[w][qr][ch0];
            float4 b = *(float4*)&Ored[w][qr][ch0 + 4];
            o[0] += a.x; o[1] += a.y; o[2] += a.z; o[3] += a.w;
            o[4] += b.x; o[5] += b.y; o[6] += b.z; o[7] += b.w;
        }
        float l = Lred2[qs][0][qr] + Lred2[qs][1][qr] + Lred2[qs][2][qr] + Lred2[qs][3][qr];
        float linv = (l > 0.f) ? 1.f / l : 0.f;
        int row = row0 + 32 * qs + qr;
        uint4 wv;
        if (Uw[row] > 0.f) {
            wv = uint4{ cvtpk(o[0]*linv, o[1]*linv), cvtpk(o[2]*linv, o[3]*linv),
                        cvtpk(o[4]*linv, o[5]*linv), cvtpk(o[6]*linv, o[7]*linv) };
        } else {
            const float* mv = meanV + win * 64 + ch0;
            wv = uint4{ cvtpk(mv[0], mv[1]), cvtpk(mv[2], mv[3]),
                        cvtpk(mv[4], mv[5]), cvtpk(mv[6], mv[7]) };
        }
        *(uint4*)(Oatt + (size_t)(win * NTOK + row) * 64 + ch0) = wv;
        __syncthreads();
    }
#undef MF32
}

// ------- refined (bf16 NHWC [p][64]) = x + Oatt @ Wc^T + bc -------
__global__ __launch_bounds__(256) void refined_kernel(
    const float* __restrict__ x, const u16_t* __restrict__ Oatt,
    const float* __restrict__ Wc, const float* __restrict__ bc,
    u16_t* __restrict__ refd)
{
    int bid = (blockIdx.x & 7) * 36 + (blockIdx.x >> 3);
    int lt = threadIdx.x & 127;
    int half = threadIdx.x >> 7;
    int t = bid * 128 + lt;
    int win = t / NTOK, n = t % NTOK;
    int p = ((win >> 2) * 48 + n / 48) * 192 + (win & 3) * 48 + n % 48;

    float ov[64];
    const uint2* o2 = (const uint2*)(Oatt + (size_t)t * 64);
    #pragma unroll
    for (int i = 0; i < 16; ++i) {
        uint2 v = o2[i];
        ov[4*i]   = bflo(v.x); ov[4*i+1] = bfhi(v.x);
        ov[4*i+2] = bflo(v.y); ov[4*i+3] = bfhi(v.y);
    }
    int dbase = half * 32;
    for (int d8 = 0; d8 < 4; ++d8) {
        u32_t wq[4];
        #pragma unroll
        for (int jp = 0; jp < 4; ++jp) {
            float r2v[2];
            #pragma unroll
            for (int j2 = 0; j2 < 2; ++j2) {
                int dd = dbase + d8 * 8 + jp * 2 + j2;
                const float* wr = Wc + dd * 64;
                float a = bc[dd] + x[(size_t)dd * HW2 + p];
                #pragma unroll
                for (int e = 0; e < 64; ++e) a += ov[e] * wr[e];
                r2v[j2] = a;
            }
            wq[jp] = cvtpk(r2v[0], r2v[1]);
        }
        *(uint4*)(refd + (size_t)p * 64 + dbase + d8 * 8) = uint4{wq[0], wq[1], wq[2], wq[3]};
    }
}

// ------- conv3x3(+bias,relu)->out0, 1x1->out1, partition map; implicit-GEMM MFMA, NHWC in -------
__global__ __launch_bounds__(256) void conv_kernel(
    const u16_t* __restrict__ refined, const u16_t* __restrict__ Wpk,
    const float* __restrict__ b3, const float* __restrict__ w4, const float* __restrict__ b4,
    float* __restrict__ out0, float* __restrict__ out1, float* __restrict__ pm)
{
    __shared__ u16_t tile[3 * 98 * 64];    // [pix][ic], slot-swizzled; 37,632 B
    __shared__ float ps[96];
    int bid = (blockIdx.x & 7) * 48 + (blockIdx.x >> 3);
    const int y  = bid >> 1;
    const int xh = (bid & 1) * 96;
    const int tid = threadIdx.x;
    if (tid < 96) ps[tid] = 0.f;

    for (int idx = tid; idx < 2352; idx += 256) {     // 294 pixels x 8 chunks
        int tg = idx & 7;
        int pix = idx >> 3;
        int r = pix / 98, cc = pix - r * 98;
        int yy = y - 1 + r, xg = xh + cc - 1;
        bf16x8 val = {0,0,0,0,0,0,0,0};
        if ((unsigned)yy < 192u && (unsigned)xg < 192u)
            val = *(const bf16x8*)(refined + ((size_t)(yy * 192 + xg)) * 64 + tg * 8);
        int slot = (tg + cc) & 7;
        *(bf16x8*)((char*)tile + (size_t)pix * 128 + slot * 16) = val;
    }
    __syncthreads();

    const int lane = tid & 63, mf = tid >> 6;
    const int ln = lane & 15, g = lane >> 4;

    bf16x8 wf[18];
    #pragma unroll
    for (int ks = 0; ks < 18; ++ks)
        wf[ks] = *(const bf16x8*)(Wpk + (size_t)((mf * 18 + ks) * 64 + lane) * 8);

    float b3v[4], w4v[4];
    #pragma unroll
    for (int r = 0; r < 4; ++r) { int oc = mf * 16 + 4 * g + r; b3v[r] = b3[oc]; w4v[r] = w4[oc]; }

    for (int nf = 0; nf < 6; ++nf) {
        int xl = nf * 16 + ln;
        f32x4 acc0 = {0.f,0.f,0.f,0.f}, acc1 = acc0;
        #pragma unroll
        for (int ks = 0; ks < 18; ++ks) {
            int tap = ks >> 1, icc = ks & 1;
            int dy = tap / 3, dx = tap - (tap / 3) * 3;
            int cc = xl + dx;
            int slot = (icc * 4 + g + cc) & 7;
            bf16x8 bfr = *(const bf16x8*)((const char*)tile + (size_t)(dy * 98 + cc) * 128 + slot * 16);
            if (ks & 1) acc1 = __builtin_amdgcn_mfma_f32_16x16x32_bf16(wf[ks], bfr, acc1, 0, 0, 0);
            else        acc0 = __builtin_amdgcn_mfma_f32_16x16x32_bf16(wf[ks], bfr, acc0, 0, 0, 0);
        }
        int xg = xh + xl;
        float s4 = 0.f;
        #pragma unroll
        for (int r = 0; r < 4; ++r) {
            int oc = mf * 16 + 4 * g + r;
            float v = fmaxf(acc0[r] + acc1[r] + b3v[r], 0.f);
            out0[(size_t)oc * HW2 + y * 192 + xg] = v;
            s4 += v * w4v[r];
        }
        atomicAdd(&ps[xl], s4);
    }
    __syncthreads();
    if (tid < 96) {
        int xg = xh + tid;
        out1[y * 192 + xg] = ps[tid] + b4[0];
        int ym = y % 48, xm = xg % 48;
        pm[y * 192 + xg] = ((ym == 0) | (ym == 47) | (xm == 0) | (xm == 47)) ? 0.6f : 1.0f;
    }
}

extern "C" void kernel_launch(void* const* d_in, const int* in_sizes, int n_in,
                              void* d_out, int out_size, void* d_ws, size_t ws_size,
                              hipStream_t stream)
{
    const float* x   = (const float*)d_in[0];
    const float* ref = (const float*)d_in[1];
    const float* unc = (const float*)d_in[2];
    const float* ipw = (const float*)d_in[3];
    const float* ipb = (const float*)d_in[4];
    const float* opw = (const float*)d_in[5];
    const float* opb = (const float*)d_in[6];
    const float* w1  = (const float*)d_in[7];
    const float* b1  = (const float*)d_in[8];
    const float* w3  = (const float*)d_in[9];
    const float* b3  = (const float*)d_in[10];
    const float* w4  = (const float*)d_in[11];
    const float* b4  = (const float*)d_in[12];

    char* ws = (char*)d_ws;
    u16_t* Qb    = (u16_t*)(ws);                  // 4,718,592
    u16_t* Kb    = (u16_t*)(ws + 4718592);        // 4,718,592
    u16_t* Vtb   = (u16_t*)(ws + 9437184);        // 4,718,592
    float* Ufp   = (float*)(ws + 14155776);       // 147,456
    float* meanV = (float*)(ws + 14303232);       // 4,096
    float* Wc    = (float*)(ws + 14307328);       // 16,384
    float* bc    = (float*)(ws + 14323712);       // 256
    u16_t* Wpk   = (u16_t*)(ws + 14323968);       // 73,728
    u16_t* Oatt  = (u16_t*)(ws + 14397696);       // 4,718,592
    u16_t* refd  = (u16_t*)(ws + 19116288);       // 4,718,592  (total 23,834,880 B)

    float* out0 = (float*)d_out;                  // r3: [1,64,192,192]
    float* out1 = out0 + 2359296;                 // out: [1,1,192,192]
    float* pmap = out0 + 2396160;                 // partition_map

    projq_kernel  <<<288, 256, 0, stream>>>(x, ipw, ipb, Qb);
    projkv_kernel <<<288, 256, 0, stream>>>(ref, unc, ipw, ipb, Kb, Vtb, Ufp);
    prep_kernel   <<<37,  256, 0, stream>>>(opw, opb, w1, b1, w3, Wc, bc, Wpk);
    meanv_kernel  <<<16,  256, 0, stream>>>(Vtb, meanV);
    attn_kernel   <<<576, 256, 0, stream>>>(Qb, Kb, Vtb, Ufp, meanV, Oatt);
    refined_kernel<<<288, 256, 0, stream>>>(x, Oatt, Wc, bc, refd);
    conv_kernel   <<<384, 256, 0, stream>>>(refd, Wpk, b3, w4, b4, out0, out1, pmap);
}

// Round 6
// 325.756 us; speedup vs baseline: 2.0527x; 1.0615x over previous
//
#include <hip/hip_runtime.h>
#include <hip/hip_bf16.h>

typedef unsigned char  u8_t;
typedef unsigned short u16_t;
typedef unsigned int   u32_t;
typedef __attribute__((ext_vector_type(8))) short bf16x8;
typedef __attribute__((ext_vector_type(4))) float f32x4;
typedef __attribute__((ext_vector_type(16))) float f32x16;

#define HW2  36864   // 192*192
#define NTOK 2304    // tokens per 48x48 window

__device__ __forceinline__ u32_t cvtpk(float a, float b) {
    union { __hip_bfloat162 h; u32_t u; } c;
    c.h = __float22bfloat162_rn(float2{a, b});
    return c.u;
}
__device__ __forceinline__ float bfhi(u32_t u) { union { u32_t u; float f; } c; c.u = u & 0xffff0000u; return c.f; }
__device__ __forceinline__ float bflo(u32_t u) { union { u32_t u; float f; } c; c.u = u << 16; return c.f; }

union U8x { u32_t u[4]; bf16x8 v; };

// ---- fused projections: blocks 0..287 = Q from x (SCL folded); 288..575 = K,V,mask from ref ----
__global__ __launch_bounds__(256) void proj_kernel(
    const float* __restrict__ x, const float* __restrict__ ref, const float* __restrict__ unc,
    const float* __restrict__ ipw, const float* __restrict__ ipb,
    u16_t* __restrict__ Q, u16_t* __restrict__ K, u16_t* __restrict__ Vt, float* __restrict__ Uf)
{
    __shared__ u32_t Tt[128][34];
    __shared__ u16_t Vl[64][136];
    const bool isQ = blockIdx.x < 288;
    int hb = isQ ? blockIdx.x : (blockIdx.x - 288);
    int bid = (hb & 7) * 36 + (hb >> 3);
    int lt = threadIdx.x & 127;
    int half = threadIdx.x >> 7;
    int t = bid * 128 + lt;
    int win = t / NTOK, n = t % NTOK;
    int p = ((win >> 2) * 48 + n / 48) * 192 + (win & 3) * 48 + n % 48;
    int dbase = half * 32;

    if (isQ) {
        const float SCL = 0.18033688011112043f;   // log2(e)/8
        float xv[64];
        #pragma unroll
        for (int c = 0; c < 64; ++c) xv[c] = x[c * HW2 + p];
        for (int d2 = 0; d2 < 16; ++d2) {
            float aq[2];
            #pragma unroll
            for (int j = 0; j < 2; ++j) {
                int dd = dbase + d2 * 2 + j;
                const float* wq = ipw + dd * 64;
                float a = ipb[dd];
                #pragma unroll
                for (int c = 0; c < 64; ++c) a += xv[c] * wq[c];
                aq[j] = a * SCL;
            }
            Tt[lt][half * 16 + d2] = cvtpk(aq[0], aq[1]);
        }
        __syncthreads();
        int tok = threadIdx.x >> 1, seg = (threadIdx.x & 1) * 16;
        u32_t* dst = (u32_t*)(Q + (size_t)(bid * 128 + tok) * 64) + seg;
        #pragma unroll
        for (int j = 0; j < 16; ++j) dst[j] = Tt[tok][seg + j];
    } else {
        // token-permute for MFMA B-frag order: swap 4-token sub-blocks 1<->2 and 5<->6 per 32
        int sub = (lt >> 2) & 7;
        int plt = (((sub ^ (sub >> 1)) & 1) ? (lt ^ 12) : lt);
        float rv[64];
        #pragma unroll
        for (int c = 0; c < 64; ++c) rv[c] = ref[c * HW2 + p];
        for (int d2 = 0; d2 < 16; ++d2) {
            float ak[2];
            #pragma unroll
            for (int j = 0; j < 2; ++j) {
                int dd = dbase + d2 * 2 + j;
                const float* wk = ipw + (64 + dd) * 64;
                const float* wv = ipw + (128 + dd) * 64;
                float a = ipb[64 + dd], b = ipb[128 + dd];
                #pragma unroll
                for (int c = 0; c < 64; ++c) { a += rv[c] * wk[c]; b += rv[c] * wv[c]; }
                ak[j] = a;
                Vl[dd][plt] = (u16_t)(cvtpk(b, 0.f) & 0xffffu);
            }
            Tt[lt][half * 16 + d2] = cvtpk(ak[0], ak[1]);
        }
        if (half == 0) Uf[t] = (unc[p] > 0.01f) ? 0.f : -100.f;   // additive exp2-bias
        __syncthreads();
        int tok = threadIdx.x >> 1, seg = (threadIdx.x & 1) * 16;
        u32_t* dst = (u32_t*)(K + (size_t)(bid * 128 + tok) * 64) + seg;
        #pragma unroll
        for (int j = 0; j < 16; ++j) dst[j] = Tt[tok][seg + j];
        int win0 = (bid * 128) / NTOK, n0 = (bid * 128) % NTOK;
        int ch = threadIdx.x >> 2, tc = (threadIdx.x & 3) * 32;
        const uint4* vsrc = (const uint4*)&Vl[ch][tc];
        uint4* vdst = (uint4*)(Vt + (size_t)win0 * 64 * NTOK + (size_t)ch * NTOK + n0 + tc);
        #pragma unroll
        for (int j = 0; j < 4; ++j) vdst[j] = vsrc[j];
    }
}

// ---- prep + meanV: b0 = fold out_proj*w1; b1..36 = conv weight pack; b37..100 = meanV from Vt ----
__global__ __launch_bounds__(256) void prepmv_kernel(
    const float* __restrict__ wop, const float* __restrict__ bop,
    const float* __restrict__ w1, const float* __restrict__ b1,
    const float* __restrict__ w3, const u16_t* __restrict__ Vt,
    float* __restrict__ Wc, float* __restrict__ bc, u16_t* __restrict__ Wpk,
    float* __restrict__ meanV)
{
    __shared__ float red[16][17];
    int tid = threadIdx.x;
    if (blockIdx.x == 0) {
        for (int idx = tid; idx < 4096; idx += 256) {
            int f = idx >> 6, d = idx & 63;
            float a = 0.f;
            for (int e = 0; e < 64; ++e) a += w1[f * 64 + e] * wop[e * 64 + d];
            Wc[idx] = a;
        }
        if (tid < 64) {
            float a = b1[tid];
            for (int e = 0; e < 64; ++e) a += w1[tid * 64 + e] * bop[e];
            bc[tid] = a;
        }
    } else if (blockIdx.x < 37) {
        for (int idx = (blockIdx.x - 1) * 256 + tid; idx < 36864; idx += 9216) {
            int i = idx & 7;
            int lane = (idx >> 3) & 63;
            int t2 = idx >> 9;
            int ks = t2 % 18, mf = t2 / 18;
            int oc = mf * 16 + (lane & 15);
            int g = lane >> 4;
            int tap = ks >> 1, icc = ks & 1;
            int dy = tap / 3, dx = tap - (tap / 3) * 3;
            int ic = icc * 32 + g * 8 + i;
            Wpk[idx] = (u16_t)(cvtpk(w3[(size_t)(oc * 64 + ic) * 9 + dy * 3 + dx], 0.f) & 0xffffu);
        }
    } else {
        int m = blockIdx.x - 37;
        int win = m >> 2, cq = m & 3;
        int chl = tid >> 4, seg = tid & 15;
        const uint2* src = (const uint2*)(Vt + (size_t)win * 64 * NTOK + (size_t)(cq * 16 + chl) * NTOK + seg * 144);
        float s = 0.f;
        for (int i = 0; i < 36; ++i) {      // 36 uint2 = 144 tokens per segment (16 segs x 144 = 2304)
            uint2 v = src[i];
            s += bflo(v.x) + bfhi(v.x) + bflo(v.y) + bfhi(v.y);
        }
        red[chl][seg] = s;
        __syncthreads();
        if (tid < 16) {
            float a = 0.f;
            #pragma unroll
            for (int k = 0; k < 16; ++k) a += red[tid][k];
            meanV[win * 64 + cq * 16 + tid] = a * (1.f / 2304.f);
        }
    }
}

// ---- attention: 32x32 MFMA, mask as MFMA-C bias, 1-deep prefetch, split-K x4 ----
__global__ __launch_bounds__(256, 2) void attn_kernel(
    const u16_t* __restrict__ Q, const u16_t* __restrict__ K, const u16_t* __restrict__ Vt,
    const float* __restrict__ Uf, const float* __restrict__ meanV, u16_t* __restrict__ Oatt)
{
    __shared__ float Ored[4][32][68];
    __shared__ float Lred2[2][4][32];

    const int bid = (blockIdx.x & 7) * 72 + (blockIdx.x >> 3);   // XCD-bijective (576%8==0)
    const int lane = threadIdx.x & 63;
    const int kq = threadIdx.x >> 6;
    const int q  = lane & 31;
    const int hi = lane >> 5;
    const int win = bid / 36;
    const int rg  = bid % 36;
    const int row0 = rg * 64;

    const u16_t* Qw = Q + (size_t)win * NTOK * 64;
    const u16_t* Kw = K + (size_t)win * NTOK * 64;
    const u16_t* Vw = Vt + (size_t)win * 64 * NTOK;
    const float* Uw = Uf + win * NTOK;

    bf16x8 qb0[4], qb1[4];
    #pragma unroll
    for (int s = 0; s < 4; ++s) {
        qb0[s] = *(const bf16x8*)(Qw + (size_t)(row0 + q) * 64 + s * 16 + hi * 8);
        qb1[s] = *(const bf16x8*)(Qw + (size_t)(row0 + 32 + q) * 64 + s * 16 + hi * 8);
    }

    const f32x16 Z16 = {0.f,0.f,0.f,0.f,0.f,0.f,0.f,0.f,0.f,0.f,0.f,0.f,0.f,0.f,0.f,0.f};
    f32x16 acc00 = Z16, acc01 = Z16, acc10 = Z16, acc11 = Z16;
    float lsum0 = 0.f, lsum1 = 0.f;

    const u16_t* kp = Kw + (size_t)(kq * 576 + q) * 64 + hi * 8;
    const u16_t* vp = Vw + (size_t)q * NTOK + kq * 576 + hi * 8;
    const float* up = Uw + kq * 576 + 4 * hi;

#define MF32(A, B, C) __builtin_amdgcn_mfma_f32_32x32x16_bf16(A, B, C, 0, 0, 0)

    bf16x8 kA0,kA1,kA2,kA3, vA0,vA1,vA2,vA3;
    bf16x8 kB0,kB1,kB2,kB3, vB0,vB1,vB2,vB3;
    float4 bA[4], bB[4];

#define LDSET(sfx, CT) { \
    const u16_t* _k = kp + (size_t)(CT) * 2048; \
    k##sfx##0 = *(const bf16x8*)(_k);      k##sfx##1 = *(const bf16x8*)(_k + 16); \
    k##sfx##2 = *(const bf16x8*)(_k + 32); k##sfx##3 = *(const bf16x8*)(_k + 48); \
    const u16_t* _v = vp + (CT) * 32; \
    v##sfx##0 = *(const bf16x8*)(_v);             v##sfx##1 = *(const bf16x8*)(_v + 16); \
    v##sfx##2 = *(const bf16x8*)(_v + 32 * NTOK); v##sfx##3 = *(const bf16x8*)(_v + 32 * NTOK + 16); \
    const float* _u = up + (CT) * 32; \
    b##sfx[0] = *(const float4*)(_u);      b##sfx[1] = *(const float4*)(_u + 8); \
    b##sfx[2] = *(const float4*)(_u + 16); b##sfx[3] = *(const float4*)(_u + 24); }

#define QS_TILE(sfx, QB, ACC0, ACC1, LSUM) { \
    f32x16 s; \
    s[0]  = b##sfx[0].x; s[1]  = b##sfx[0].y; s[2]  = b##sfx[0].z; s[3]  = b##sfx[0].w; \
    s[4]  = b##sfx[1].x; s[5]  = b##sfx[1].y; s[6]  = b##sfx[1].z; s[7]  = b##sfx[1].w; \
    s[8]  = b##sfx[2].x; s[9]  = b##sfx[2].y; s[10] = b##sfx[2].z; s[11] = b##sfx[2].w; \
    s[12] = b##sfx[3].x; s[13] = b##sfx[3].y; s[14] = b##sfx[3].z; s[15] = b##sfx[3].w; \
    s = MF32(k##sfx##0, QB[0], s); s = MF32(k##sfx##1, QB[1], s); \
    s = MF32(k##sfx##2, QB[2], s); s = MF32(k##sfx##3, QB[3], s); \
    float pv[16]; float lls = 0.f; \
    _Pragma("unroll") for (int r = 0; r < 16; ++r) { pv[r] = __builtin_exp2f(s[r]); lls += pv[r]; } \
    LSUM += lls; \
    U8x f0, f1; \
    _Pragma("unroll") for (int j = 0; j < 4; ++j) { \
        f0.u[j] = cvtpk(pv[2 * j], pv[2 * j + 1]); \
        f1.u[j] = cvtpk(pv[8 + 2 * j], pv[8 + 2 * j + 1]); } \
    ACC0 = MF32(v##sfx##0, f0.v, ACC0); ACC0 = MF32(v##sfx##1, f1.v, ACC0); \
    ACC1 = MF32(v##sfx##2, f0.v, ACC1); ACC1 = MF32(v##sfx##3, f1.v, ACC1); }

#define BODY(sfx) { QS_TILE(sfx, qb0, acc00, acc01, lsum0) QS_TILE(sfx, qb1, acc10, acc11, lsum1) }

    LDSET(A, 0)
    #pragma unroll 1
    for (int tt = 0; tt < 9; ++tt) {
        LDSET(B, 2 * tt + 1)
        BODY(A)
        if (tt < 8) LDSET(A, 2 * tt + 2)
        BODY(B)
    }
#undef BODY
#undef QS_TILE
#undef LDSET

    float l0 = lsum0 + __shfl_xor(lsum0, 32);
    float l1 = lsum1 + __shfl_xor(lsum1, 32);
    if (hi == 0) { Lred2[0][kq][q] = l0; Lred2[1][kq][q] = l1; }

    const int qr = threadIdx.x >> 3;
    const int ch0 = (threadIdx.x & 7) * 8;

    #pragma unroll
    for (int qs = 0; qs < 2; ++qs) {
        f32x16 a0 = qs ? acc10 : acc00;
        f32x16 a1 = qs ? acc11 : acc01;
        #pragma unroll
        for (int rr = 0; rr < 4; ++rr) {
            float4 v0 = { a0[4*rr], a0[4*rr+1], a0[4*rr+2], a0[4*rr+3] };
            float4 v1 = { a1[4*rr], a1[4*rr+1], a1[4*rr+2], a1[4*rr+3] };
            *(float4*)&Ored[kq][q][8 * rr + 4 * hi]      = v0;
            *(float4*)&Ored[kq][q][32 + 8 * rr + 4 * hi] = v1;
        }
        __syncthreads();
        float o[8] = {0.f,0.f,0.f,0.f,0.f,0.f,0.f,0.f};
        #pragma unroll
        for (int w = 0; w < 4; ++w) {
            float4 a = *(float4*)&Ored[w][qr][ch0];
            float4 b = *(float4*)&Ored[w][qr][ch0 + 4];
            o[0] += a.x; o[1] += a.y; o[2] += a.z; o[3] += a.w;
            o[4] += b.x; o[5] += b.y; o[6] += b.z; o[7] += b.w;
        }
        float l = Lred2[qs][0][qr] + Lred2[qs][1][qr] + Lred2[qs][2][qr] + Lred2[qs][3][qr];
        float linv = (l > 0.f) ? 1.f / l : 0.f;
        int row = row0 + 32 * qs + qr;
        uint4 wv;
        if (Uw[row] == 0.f) {   // uncertain row
            wv = uint4{ cvtpk(o[0]*linv, o[1]*linv), cvtpk(o[2]*linv, o[3]*linv),
                        cvtpk(o[4]*linv, o[5]*linv), cvtpk(o[6]*linv, o[7]*linv) };
        } else {
            const float* mv = meanV + win * 64 + ch0;
            wv = uint4{ cvtpk(mv[0], mv[1]), cvtpk(mv[2], mv[3]),
                        cvtpk(mv[4], mv[5]), cvtpk(mv[6], mv[7]) };
        }
        *(uint4*)(Oatt + (size_t)(win * NTOK + row) * 64 + ch0) = wv;
        __syncthreads();
    }
#undef MF32
}

// ------- refined (bf16 NHWC [p][64]) = x + Oatt @ Wc^T + bc -------
__global__ __launch_bounds__(256) void refined_kernel(
    const float* __restrict__ x, const u16_t* __restrict__ Oatt,
    const float* __restrict__ Wc, const float* __restrict__ bc,
    u16_t* __restrict__ refd)
{
    int bid = (blockIdx.x & 7) * 36 + (blockIdx.x >> 3);
    int lt = threadIdx.x & 127;
    int half = threadIdx.x >> 7;
    int t = bid * 128 + lt;
    int win = t / NTOK, n = t % NTOK;
    int p = ((win >> 2) * 48 + n / 48) * 192 + (win & 3) * 48 + n % 48;

    float ov[64];
    const uint2* o2 = (const uint2*)(Oatt + (size_t)t * 64);
    #pragma unroll
    for (int i = 0; i < 16; ++i) {
        uint2 v = o2[i];
        ov[4*i]   = bflo(v.x); ov[4*i+1] = bfhi(v.x);
        ov[4*i+2] = bflo(v.y); ov[4*i+3] = bfhi(v.y);
    }
    int dbase = half * 32;
    for (int d8 = 0; d8 < 4; ++d8) {
        u32_t wq[4];
        #pragma unroll
        for (int jp = 0; jp < 4; ++jp) {
            float r2v[2];
            #pragma unroll
            for (int j2 = 0; j2 < 2; ++j2) {
                int dd = dbase + d8 * 8 + jp * 2 + j2;
                const float* wr = Wc + dd * 64;
                float a = bc[dd] + x[(size_t)dd * HW2 + p];
                #pragma unroll
                for (int e = 0; e < 64; ++e) a += ov[e] * wr[e];
                r2v[j2] = a;
            }
            wq[jp] = cvtpk(r2v[0], r2v[1]);
        }
        *(uint4*)(refd + (size_t)p * 64 + dbase + d8 * 8) = uint4{wq[0], wq[1], wq[2], wq[3]};
    }
}

// ------- conv3x3(+bias,relu)->out0, 1x1->out1, partition map; implicit-GEMM MFMA, NHWC in -------
__global__ __launch_bounds__(256) void conv_kernel(
    const u16_t* __restrict__ refined, const u16_t* __restrict__ Wpk,
    const float* __restrict__ b3, const float* __restrict__ w4, const float* __restrict__ b4,
    float* __restrict__ out0, float* __restrict__ out1, float* __restrict__ pm)
{
    __shared__ u16_t tile[3 * 50 * 64];    // [pix][ic], slot-swizzled; 19,200 B
    __shared__ float ps[48];
    int bid = (blockIdx.x & 7) * 96 + (blockIdx.x >> 3);
    const int y  = bid >> 2;
    const int x0 = (bid & 3) * 48;
    const int tid = threadIdx.x;
    if (tid < 48) ps[tid] = 0.f;

    for (int idx = tid; idx < 1200; idx += 256) {     // 150 pixels x 8 chunks
        int tg = idx & 7;
        int pix = idx >> 3;
        int r = pix / 50, cc = pix - r * 50;
        int yy = y - 1 + r, xg = x0 - 1 + cc;
        bf16x8 val = {0,0,0,0,0,0,0,0};
        if ((unsigned)yy < 192u && (unsigned)xg < 192u)
            val = *(const bf16x8*)(refined + ((size_t)(yy * 192 + xg)) * 64 + tg * 8);
        int slot = (tg + cc) & 7;
        *(bf16x8*)((char*)tile + (size_t)pix * 128 + slot * 16) = val;
    }
    __syncthreads();

    const int lane = tid & 63, mf = tid >> 6;
    const int ln = lane & 15, g = lane >> 4;

    bf16x8 wf[18];
    #pragma unroll
    for (int ks = 0; ks < 18; ++ks)
        wf[ks] = *(const bf16x8*)(Wpk + (size_t)((mf * 18 + ks) * 64 + lane) * 8);

    float b3v[4], w4v[4];
    #pragma unroll
    for (int r = 0; r < 4; ++r) { int oc = mf * 16 + 4 * g + r; b3v[r] = b3[oc]; w4v[r] = w4[oc]; }

    for (int nf = 0; nf < 3; ++nf) {
        int xl = nf * 16 + ln;
        f32x4 acc0 = {0.f,0.f,0.f,0.f}, acc1 = acc0;
        #pragma unroll
        for (int ks = 0; ks < 18; ++ks) {
            int tap = ks >> 1, icc = ks & 1;
            int dy = tap / 3, dx = tap - (tap / 3) * 3;
            int cc = xl + dx;
            int slot = (icc * 4 + g + cc) & 7;
            bf16x8 bfr = *(const bf16x8*)((const char*)tile + (size_t)(dy * 50 + cc) * 128 + slot * 16);
            if (ks & 1) acc1 = __builtin_amdgcn_mfma_f32_16x16x32_bf16(wf[ks], bfr, acc1, 0, 0, 0);
            else        acc0 = __builtin_amdgcn_mfma_f32_16x16x32_bf16(wf[ks], bfr, acc0, 0, 0, 0);
        }
        int xg = x0 + xl;
        float s4 = 0.f;
        #pragma unroll
        for (int r = 0; r < 4; ++r) {
            int oc = mf * 16 + 4 * g + r;
            float v = fmaxf(acc0[r] + acc1[r] + b3v[r], 0.f);
            out0[(size_t)oc * HW2 + y * 192 + xg] = v;
            s4 += v * w4v[r];
        }
        atomicAdd(&ps[xl], s4);
    }
    __syncthreads();
    if (tid < 48) {
        int xg = x0 + tid;
        out1[y * 192 + xg] = ps[tid] + b4[0];
        int ym = y % 48, xm = xg % 48;
        pm[y * 192 + xg] = ((ym == 0) | (ym == 47) | (xm == 0) | (xm == 47)) ? 0.6f : 1.0f;
    }
}

extern "C" void kernel_launch(void* const* d_in, const int* in_sizes, int n_in,
                              void* d_out, int out_size, void* d_ws, size_t ws_size,
                              hipStream_t stream)
{
    const float* x   = (const float*)d_in[0];
    const float* ref = (const float*)d_in[1];
    const float* unc = (const float*)d_in[2];
    const float* ipw = (const float*)d_in[3];
    const float* ipb = (const float*)d_in[4];
    const float* opw = (const float*)d_in[5];
    const float* opb = (const float*)d_in[6];
    const float* w1  = (const float*)d_in[7];
    const float* b1  = (const float*)d_in[8];
    const float* w3  = (const float*)d_in[9];
    const float* b3  = (const float*)d_in[10];
    const float* w4  = (const float*)d_in[11];
    const float* b4  = (const float*)d_in[12];

    char* ws = (char*)d_ws;
    u16_t* Qb    = (u16_t*)(ws);                  // 4,718,592
    u16_t* Kb    = (u16_t*)(ws + 4718592);        // 4,718,592
    u16_t* Vtb   = (u16_t*)(ws + 9437184);        // 4,718,592
    float* Ufp   = (float*)(ws + 14155776);       // 147,456
    float* meanV = (float*)(ws + 14303232);       // 4,096
    float* Wc    = (float*)(ws + 14307328);       // 16,384
    float* bc    = (float*)(ws + 14323712);       // 256
    u16_t* Wpk   = (u16_t*)(ws + 14323968);       // 73,728
    u16_t* Oatt  = (u16_t*)(ws + 14397696);       // 4,718,592
    u16_t* refd  = (u16_t*)(ws + 19116288);       // 4,718,592  (total 23,834,880 B)

    float* out0 = (float*)d_out;                  // r3: [1,64,192,192]
    float* out1 = out0 + 2359296;                 // out: [1,1,192,192]
    float* pmap = out0 + 2396160;                 // partition_map

    proj_kernel   <<<576, 256, 0, stream>>>(x, ref, unc, ipw, ipb, Qb, Kb, Vtb, Ufp);
    prepmv_kernel <<<101, 256, 0, stream>>>(opw, opb, w1, b1, w3, Vtb, Wc, bc, Wpk, meanV);
    attn_kernel   <<<576, 256, 0, stream>>>(Qb, Kb, Vtb, Ufp, meanV, Oatt);
    refined_kernel<<<288, 256, 0, stream>>>(x, Oatt, Wc, bc, refd);
    conv_kernel   <<<768, 256, 0, stream>>>(refd, Wpk, b3, w4, b4, out0, out1, pmap);
}

// Round 7
// 210.489 us; speedup vs baseline: 3.1768x; 1.5476x over previous
//
#include <hip/hip_runtime.h>
#include <hip/hip_bf16.h>

typedef unsigned char  u8_t;
typedef unsigned short u16_t;
typedef unsigned int   u32_t;
typedef __attribute__((ext_vector_type(8))) short bf16x8;
typedef __attribute__((ext_vector_type(4))) float f32x4;
typedef __attribute__((ext_vector_type(16))) float f32x16;

#define HW2  36864   // 192*192
#define NTOK 2304    // tokens per 48x48 window

__device__ __forceinline__ u32_t cvtpk(float a, float b) {
    union { __hip_bfloat162 h; u32_t u; } c;
    c.h = __float22bfloat162_rn(float2{a, b});
    return c.u;
}
__device__ __forceinline__ float bfhi(u32_t u) { union { u32_t u; float f; } c; c.u = u & 0xffff0000u; return c.f; }
__device__ __forceinline__ float bflo(u32_t u) { union { u32_t u; float f; } c; c.u = u << 16; return c.f; }

union U8x { u32_t u[4]; bf16x8 v; };

#define MF32(A, B, C) __builtin_amdgcn_mfma_f32_32x32x16_bf16(A, B, C, 0, 0, 0)

// ---- MFMA projections: even blocks = Q from x; odd blocks = K,V,mask from ref ----
// 64 tokens/block; wave = (tile of 32 tokens, role). Out C-layout: col=lane&31=token,
// row=(r&3)+8*(r>>2)+4*hi = channel. Q/K go через LDS transpose to [tok][64] bf16.
__global__ __launch_bounds__(256) void proj_kernel(
    const float* __restrict__ x, const float* __restrict__ ref, const float* __restrict__ unc,
    const float* __restrict__ ipw, const float* __restrict__ ipb,
    u16_t* __restrict__ Q, u16_t* __restrict__ K, u16_t* __restrict__ Vt, float* __restrict__ Uf)
{
    __shared__ u32_t Tt[64][33];
    const int side = blockIdx.x & 1;             // 0: Q,  1: K/V
    const int hb = blockIdx.x >> 1;              // 0..575
    const int bid = (hb & 7) * 72 + (hb >> 3);   // XCD-bijective (576%8==0)
    const int tokb = bid * 64;
    const int win = tokb / NTOK;
    const int n0 = tokb - win * NTOK;

    const int w = threadIdx.x >> 6;
    const int lane = threadIdx.x & 63;
    const int tile = w & 1;
    const int sel = w >> 1;                      // Q: octile; KV: 0=K 1=V
    const int q = lane & 31;
    const int hi = lane >> 5;

    const float* in = side ? ref : x;
    int n = n0 + tile * 32 + q;
    int p = ((win >> 2) * 48 + n / 48) * 192 + (win & 3) * 48 + n % 48;

    // B-frags: 4 k-chunks of 16 channels, gathered per-channel (coalesced across lanes)
    bf16x8 bfr[4];
    #pragma unroll
    for (int kc = 0; kc < 4; ++kc) {
        float v[8];
        #pragma unroll
        for (int i = 0; i < 8; ++i) v[i] = in[(size_t)(kc * 16 + hi * 8 + i) * HW2 + p];
        U8x pk;
        #pragma unroll
        for (int j = 0; j < 4; ++j) pk.u[j] = cvtpk(v[2 * j], v[2 * j + 1]);
        bfr[kc] = pk.v;
    }

    if (side == 0) {
        // ---- Q octile `sel`, scale folded into W and bias ----
        const float SCL = 0.18033688011112043f;   // log2(e)/8
        const int oct = sel;
        f32x16 acc;
        #pragma unroll
        for (int r = 0; r < 16; ++r)
            acc[r] = ipb[oct * 32 + (r & 3) + 8 * (r >> 2) + 4 * hi] * SCL;
        #pragma unroll
        for (int kc = 0; kc < 4; ++kc) {
            const float* wr = ipw + (size_t)(oct * 32 + q) * 64 + kc * 16 + hi * 8;
            U8x a;
            #pragma unroll
            for (int j = 0; j < 4; ++j) a.u[j] = cvtpk(wr[2 * j] * SCL, wr[2 * j + 1] * SCL);
            acc = MF32(a.v, bfr[kc], acc);
        }
        #pragma unroll
        for (int rp = 0; rp < 8; ++rp) {
            int j = (rp & 1) + ((rp >> 1) << 2) + 2 * hi + (oct << 4);
            Tt[tile * 32 + q][j] = cvtpk(acc[2 * rp], acc[2 * rp + 1]);
        }
    } else if (sel == 0) {
        // ---- K, both octiles ----
        #pragma unroll
        for (int oct = 0; oct < 2; ++oct) {
            f32x16 acc;
            #pragma unroll
            for (int r = 0; r < 16; ++r)
                acc[r] = ipb[64 + oct * 32 + (r & 3) + 8 * (r >> 2) + 4 * hi];
            #pragma unroll
            for (int kc = 0; kc < 4; ++kc) {
                const float* wr = ipw + (size_t)(64 + oct * 32 + q) * 64 + kc * 16 + hi * 8;
                U8x a;
                #pragma unroll
                for (int j = 0; j < 4; ++j) a.u[j] = cvtpk(wr[2 * j], wr[2 * j + 1]);
                acc = MF32(a.v, bfr[kc], acc);
            }
            #pragma unroll
            for (int rp = 0; rp < 8; ++rp) {
                int j = (rp & 1) + ((rp >> 1) << 2) + 2 * hi + (oct << 4);
                Tt[tile * 32 + q][j] = cvtpk(acc[2 * rp], acc[2 * rp + 1]);
            }
        }
    } else {
        // ---- V, both octiles: transposed + token-permuted scattered stores; plus mask ----
        int sub = (q >> 2) & 7;
        int pq = (((sub ^ (sub >> 1)) & 1) ? (q ^ 12) : q);
        u16_t* vb = Vt + (size_t)win * 64 * NTOK + n0 + tile * 32 + pq;
        #pragma unroll
        for (int oct = 0; oct < 2; ++oct) {
            f32x16 acc;
            #pragma unroll
            for (int r = 0; r < 16; ++r)
                acc[r] = ipb[128 + oct * 32 + (r & 3) + 8 * (r >> 2) + 4 * hi];
            #pragma unroll
            for (int kc = 0; kc < 4; ++kc) {
                const float* wr = ipw + (size_t)(128 + oct * 32 + q) * 64 + kc * 16 + hi * 8;
                U8x a;
                #pragma unroll
                for (int j = 0; j < 4; ++j) a.u[j] = cvtpk(wr[2 * j], wr[2 * j + 1]);
                acc = MF32(a.v, bfr[kc], acc);
            }
            #pragma unroll
            for (int r = 0; r < 16; ++r) {
                int ch = oct * 32 + (r & 3) + 8 * (r >> 2) + 4 * hi;
                vb[(size_t)ch * NTOK] = (u16_t)(cvtpk(acc[r], 0.f) & 0xffffu);
            }
        }
        if (hi == 0) Uf[tokb + tile * 32 + q] = (unc[p] > 0.01f) ? 0.f : -100.f;
    }
    __syncthreads();

    // coalesced store of Tt -> Q or K  ([tok][64] bf16)
    {
        u16_t* dst = side ? K : Q;
        int tok = threadIdx.x >> 2, s8 = (threadIdx.x & 3) * 8;
        u32_t v0[4], v1[4];
        #pragma unroll
        for (int j = 0; j < 4; ++j) { v0[j] = Tt[tok][s8 + j]; v1[j] = Tt[tok][s8 + 4 + j]; }
        u32_t* d = (u32_t*)(dst + (size_t)(tokb + tok) * 64) + s8;
        *(uint4*)d       = uint4{v0[0], v0[1], v0[2], v0[3]};
        *(uint4*)(d + 4) = uint4{v1[0], v1[1], v1[2], v1[3]};
    }
}

// ---- prep + meanV: b0 = fold out_proj*w1; b1..36 = conv weight pack; b37..100 = meanV from Vt ----
__global__ __launch_bounds__(256) void prepmv_kernel(
    const float* __restrict__ wop, const float* __restrict__ bop,
    const float* __restrict__ w1, const float* __restrict__ b1,
    const float* __restrict__ w3, const u16_t* __restrict__ Vt,
    float* __restrict__ Wc, float* __restrict__ bc, u16_t* __restrict__ Wpk,
    float* __restrict__ meanV)
{
    __shared__ float red[16][17];
    int tid = threadIdx.x;
    if (blockIdx.x == 0) {
        for (int idx = tid; idx < 4096; idx += 256) {
            int f = idx >> 6, d = idx & 63;
            float a = 0.f;
            for (int e = 0; e < 64; ++e) a += w1[f * 64 + e] * wop[e * 64 + d];
            Wc[idx] = a;
        }
        if (tid < 64) {
            float a = b1[tid];
            for (int e = 0; e < 64; ++e) a += w1[tid * 64 + e] * bop[e];
            bc[tid] = a;
        }
    } else if (blockIdx.x < 37) {
        for (int idx = (blockIdx.x - 1) * 256 + tid; idx < 36864; idx += 9216) {
            int i = idx & 7;
            int lane = (idx >> 3) & 63;
            int t2 = idx >> 9;
            int ks = t2 % 18, mf = t2 / 18;
            int oc = mf * 16 + (lane & 15);
            int g = lane >> 4;
            int tap = ks >> 1, icc = ks & 1;
            int dy = tap / 3, dx = tap - (tap / 3) * 3;
            int ic = icc * 32 + g * 8 + i;
            Wpk[idx] = (u16_t)(cvtpk(w3[(size_t)(oc * 64 + ic) * 9 + dy * 3 + dx], 0.f) & 0xffffu);
        }
    } else {
        int m = blockIdx.x - 37;
        int win = m >> 2, cq = m & 3;
        int chl = tid >> 4, seg = tid & 15;
        const uint2* src = (const uint2*)(Vt + (size_t)win * 64 * NTOK + (size_t)(cq * 16 + chl) * NTOK + seg * 144);
        float s = 0.f;
        for (int i = 0; i < 36; ++i) {      // 36 uint2 = 144 tokens per segment
            uint2 v = src[i];
            s += bflo(v.x) + bfhi(v.x) + bflo(v.y) + bfhi(v.y);
        }
        red[chl][seg] = s;
        __syncthreads();
        if (tid < 16) {
            float a = 0.f;
            #pragma unroll
            for (int k = 0; k < 16; ++k) a += red[tid][k];
            meanV[win * 64 + cq * 16 + tid] = a * (1.f / 2304.f);
        }
    }
}

// ---- attention: 32x32 MFMA, mask as MFMA-C bias, 1-deep prefetch, split-K x4 ----
__global__ __launch_bounds__(256, 2) void attn_kernel(
    const u16_t* __restrict__ Q, const u16_t* __restrict__ K, const u16_t* __restrict__ Vt,
    const float* __restrict__ Uf, const float* __restrict__ meanV, u16_t* __restrict__ Oatt)
{
    __shared__ float Ored[4][32][68];
    __shared__ float Lred2[2][4][32];

    const int bid = (blockIdx.x & 7) * 72 + (blockIdx.x >> 3);   // XCD-bijective (576%8==0)
    const int lane = threadIdx.x & 63;
    const int kq = threadIdx.x >> 6;
    const int q  = lane & 31;
    const int hi = lane >> 5;
    const int win = bid / 36;
    const int rg  = bid % 36;
    const int row0 = rg * 64;

    const u16_t* Qw = Q + (size_t)win * NTOK * 64;
    const u16_t* Kw = K + (size_t)win * NTOK * 64;
    const u16_t* Vw = Vt + (size_t)win * 64 * NTOK;
    const float* Uw = Uf + win * NTOK;

    bf16x8 qb0[4], qb1[4];
    #pragma unroll
    for (int s = 0; s < 4; ++s) {
        qb0[s] = *(const bf16x8*)(Qw + (size_t)(row0 + q) * 64 + s * 16 + hi * 8);
        qb1[s] = *(const bf16x8*)(Qw + (size_t)(row0 + 32 + q) * 64 + s * 16 + hi * 8);
    }

    const f32x16 Z16 = {0.f,0.f,0.f,0.f,0.f,0.f,0.f,0.f,0.f,0.f,0.f,0.f,0.f,0.f,0.f,0.f};
    f32x16 acc00 = Z16, acc01 = Z16, acc10 = Z16, acc11 = Z16;
    float lsum0 = 0.f, lsum1 = 0.f;

    const u16_t* kp = Kw + (size_t)(kq * 576 + q) * 64 + hi * 8;
    const u16_t* vp = Vw + (size_t)q * NTOK + kq * 576 + hi * 8;
    const float* up = Uw + kq * 576 + 4 * hi;

    bf16x8 kA0,kA1,kA2,kA3, vA0,vA1,vA2,vA3;
    bf16x8 kB0,kB1,kB2,kB3, vB0,vB1,vB2,vB3;
    float4 bA[4], bB[4];

#define LDSET(sfx, CT) { \
    const u16_t* _k = kp + (size_t)(CT) * 2048; \
    k##sfx##0 = *(const bf16x8*)(_k);      k##sfx##1 = *(const bf16x8*)(_k + 16); \
    k##sfx##2 = *(const bf16x8*)(_k + 32); k##sfx##3 = *(const bf16x8*)(_k + 48); \
    const u16_t* _v = vp + (CT) * 32; \
    v##sfx##0 = *(const bf16x8*)(_v);             v##sfx##1 = *(const bf16x8*)(_v + 16); \
    v##sfx##2 = *(const bf16x8*)(_v + 32 * NTOK); v##sfx##3 = *(const bf16x8*)(_v + 32 * NTOK + 16); \
    const float* _u = up + (CT) * 32; \
    b##sfx[0] = *(const float4*)(_u);      b##sfx[1] = *(const float4*)(_u + 8); \
    b##sfx[2] = *(const float4*)(_u + 16); b##sfx[3] = *(const float4*)(_u + 24); }

#define QS_TILE(sfx, QB, ACC0, ACC1, LSUM) { \
    f32x16 s; \
    s[0]  = b##sfx[0].x; s[1]  = b##sfx[0].y; s[2]  = b##sfx[0].z; s[3]  = b##sfx[0].w; \
    s[4]  = b##sfx[1].x; s[5]  = b##sfx[1].y; s[6]  = b##sfx[1].z; s[7]  = b##sfx[1].w; \
    s[8]  = b##sfx[2].x; s[9]  = b##sfx[2].y; s[10] = b##sfx[2].z; s[11] = b##sfx[2].w; \
    s[12] = b##sfx[3].x; s[13] = b##sfx[3].y; s[14] = b##sfx[3].z; s[15] = b##sfx[3].w; \
    s = MF32(k##sfx##0, QB[0], s); s = MF32(k##sfx##1, QB[1], s); \
    s = MF32(k##sfx##2, QB[2], s); s = MF32(k##sfx##3, QB[3], s); \
    float pv[16]; float lls = 0.f; \
    _Pragma("unroll") for (int r = 0; r < 16; ++r) { pv[r] = __builtin_exp2f(s[r]); lls += pv[r]; } \
    LSUM += lls; \
    U8x f0, f1; \
    _Pragma("unroll") for (int j = 0; j < 4; ++j) { \
        f0.u[j] = cvtpk(pv[2 * j], pv[2 * j + 1]); \
        f1.u[j] = cvtpk(pv[8 + 2 * j], pv[8 + 2 * j + 1]); } \
    ACC0 = MF32(v##sfx##0, f0.v, ACC0); ACC0 = MF32(v##sfx##1, f1.v, ACC0); \
    ACC1 = MF32(v##sfx##2, f0.v, ACC1); ACC1 = MF32(v##sfx##3, f1.v, ACC1); }

#define BODY(sfx) { QS_TILE(sfx, qb0, acc00, acc01, lsum0) QS_TILE(sfx, qb1, acc10, acc11, lsum1) }

    LDSET(A, 0)
    #pragma unroll 1
    for (int tt = 0; tt < 9; ++tt) {
        LDSET(B, 2 * tt + 1)
        BODY(A)
        if (tt < 8) LDSET(A, 2 * tt + 2)
        BODY(B)
    }
#undef BODY
#undef QS_TILE
#undef LDSET

    float l0 = lsum0 + __shfl_xor(lsum0, 32);
    float l1 = lsum1 + __shfl_xor(lsum1, 32);
    if (hi == 0) { Lred2[0][kq][q] = l0; Lred2[1][kq][q] = l1; }

    const int qr = threadIdx.x >> 3;
    const int ch0 = (threadIdx.x & 7) * 8;

    #pragma unroll
    for (int qs = 0; qs < 2; ++qs) {
        f32x16 a0 = qs ? acc10 : acc00;
        f32x16 a1 = qs ? acc11 : acc01;
        #pragma unroll
        for (int rr = 0; rr < 4; ++rr) {
            float4 v0 = { a0[4*rr], a0[4*rr+1], a0[4*rr+2], a0[4*rr+3] };
            float4 v1 = { a1[4*rr], a1[4*rr+1], a1[4*rr+2], a1[4*rr+3] };
            *(float4*)&Ored[kq][q][8 * rr + 4 * hi]      = v0;
            *(float4*)&Ored[kq][q][32 + 8 * rr + 4 * hi] = v1;
        }
        __syncthreads();
        float o[8] = {0.f,0.f,0.f,0.f,0.f,0.f,0.f,0.f};
        #pragma unroll
        for (int w = 0; w < 4; ++w) {
            float4 a = *(float4*)&Ored[w][qr][ch0];
            float4 b = *(float4*)&Ored[w][qr][ch0 + 4];
            o[0] += a.x; o[1] += a.y; o[2] += a.z; o[3] += a.w;
            o[4] += b.x; o[5] += b.y; o[6] += b.z; o[7] += b.w;
        }
        float l = Lred2[qs][0][qr] + Lred2[qs][1][qr] + Lred2[qs][2][qr] + Lred2[qs][3][qr];
        float linv = (l > 0.f) ? 1.f / l : 0.f;
        int row = row0 + 32 * qs + qr;
        uint4 wv;
        if (Uw[row] == 0.f) {   // uncertain row
            wv = uint4{ cvtpk(o[0]*linv, o[1]*linv), cvtpk(o[2]*linv, o[3]*linv),
                        cvtpk(o[4]*linv, o[5]*linv), cvtpk(o[6]*linv, o[7]*linv) };
        } else {
            const float* mv = meanV + win * 64 + ch0;
            wv = uint4{ cvtpk(mv[0], mv[1]), cvtpk(mv[2], mv[3]),
                        cvtpk(mv[4], mv[5]), cvtpk(mv[6], mv[7]) };
        }
        *(uint4*)(Oatt + (size_t)(win * NTOK + row) * 64 + ch0) = wv;
        __syncthreads();
    }
}

// ---- refined (bf16 NHWC [p][64]) = x + Oatt @ Wc^T + bc  — MFMA GEMM ----
__global__ __launch_bounds__(256) void refined_kernel(
    const float* __restrict__ x, const u16_t* __restrict__ Oatt,
    const float* __restrict__ Wc, const float* __restrict__ bc,
    u16_t* __restrict__ refd)
{
    __shared__ u32_t Tt[64][33];
    const int bid = (blockIdx.x & 7) * 72 + (blockIdx.x >> 3);   // 576 blocks
    const int tokb = bid * 64;
    const int win = tokb / NTOK;
    const int n0 = tokb - win * NTOK;

    const int w = threadIdx.x >> 6;
    const int lane = threadIdx.x & 63;
    const int tile = w & 1;
    const int oct = w >> 1;
    const int q = lane & 31;
    const int hi = lane >> 5;

    int n = n0 + tile * 32 + q;
    int p = ((win >> 2) * 48 + n / 48) * 192 + (win & 3) * 48 + n % 48;

    // B-frags straight from Oatt (bf16 token-major)
    const u16_t* ob = Oatt + (size_t)(tokb + tile * 32 + q) * 64 + hi * 8;
    bf16x8 bfr[4];
    #pragma unroll
    for (int kc = 0; kc < 4; ++kc) bfr[kc] = *(const bf16x8*)(ob + kc * 16);

    f32x16 acc;
    #pragma unroll
    for (int r = 0; r < 16; ++r)
        acc[r] = bc[oct * 32 + (r & 3) + 8 * (r >> 2) + 4 * hi];
    #pragma unroll
    for (int kc = 0; kc < 4; ++kc) {
        const float* wr = Wc + (size_t)(oct * 32 + q) * 64 + kc * 16 + hi * 8;
        U8x a;
        #pragma unroll
        for (int j = 0; j < 4; ++j) a.u[j] = cvtpk(wr[2 * j], wr[2 * j + 1]);
        acc = MF32(a.v, bfr[kc], acc);
    }
    // add residual x and pack pairs into LDS
    #pragma unroll
    for (int rp = 0; rp < 8; ++rp) {
        int ch = oct * 32 + (2 * rp & 3) + 8 * (rp >> 1) + 4 * hi;
        float xa = x[(size_t)ch * HW2 + p] + acc[2 * rp];
        float xb = x[(size_t)(ch + 1) * HW2 + p] + acc[2 * rp + 1];
        int j = (rp & 1) + ((rp >> 1) << 2) + 2 * hi + (oct << 4);
        Tt[tile * 32 + q][j] = cvtpk(xa, xb);
    }
    __syncthreads();

    // coalesced NHWC store (pixel-indexed)
    {
        int tok = threadIdx.x >> 2, s8 = (threadIdx.x & 3) * 8;
        int nn = n0 + tok;
        int pp = ((win >> 2) * 48 + nn / 48) * 192 + (win & 3) * 48 + nn % 48;
        u32_t v0[4], v1[4];
        #pragma unroll
        for (int j = 0; j < 4; ++j) { v0[j] = Tt[tok][s8 + j]; v1[j] = Tt[tok][s8 + 4 + j]; }
        u32_t* d = (u32_t*)(refd + (size_t)pp * 64) + s8;
        *(uint4*)d       = uint4{v0[0], v0[1], v0[2], v0[3]};
        *(uint4*)(d + 4) = uint4{v1[0], v1[1], v1[2], v1[3]};
    }
}

// ------- conv3x3(+bias,relu)->out0, 1x1->out1, partition map; implicit-GEMM MFMA, NHWC in -------
__global__ __launch_bounds__(256) void conv_kernel(
    const u16_t* __restrict__ refined, const u16_t* __restrict__ Wpk,
    const float* __restrict__ b3, const float* __restrict__ w4, const float* __restrict__ b4,
    float* __restrict__ out0, float* __restrict__ out1, float* __restrict__ pm)
{
    __shared__ u16_t tile[3 * 50 * 64];    // [pix][ic], slot-swizzled; 19,200 B
    __shared__ float ps[48];
    int bid = (blockIdx.x & 7) * 96 + (blockIdx.x >> 3);
    const int y  = bid >> 2;
    const int x0 = (bid & 3) * 48;
    const int tid = threadIdx.x;
    if (tid < 48) ps[tid] = 0.f;

    for (int idx = tid; idx < 1200; idx += 256) {     // 150 pixels x 8 chunks
        int tg = idx & 7;
        int pix = idx >> 3;
        int r = pix / 50, cc = pix - r * 50;
        int yy = y - 1 + r, xg = x0 - 1 + cc;
        bf16x8 val = {0,0,0,0,0,0,0,0};
        if ((unsigned)yy < 192u && (unsigned)xg < 192u)
            val = *(const bf16x8*)(refined + ((size_t)(yy * 192 + xg)) * 64 + tg * 8);
        int slot = (tg + cc) & 7;
        *(bf16x8*)((char*)tile + (size_t)pix * 128 + slot * 16) = val;
    }
    __syncthreads();

    const int lane = tid & 63, mf = tid >> 6;
    const int ln = lane & 15, g = lane >> 4;

    bf16x8 wf[18];
    #pragma unroll
    for (int ks = 0; ks < 18; ++ks)
        wf[ks] = *(const bf16x8*)(Wpk + (size_t)((mf * 18 + ks) * 64 + lane) * 8);

    float b3v[4], w4v[4];
    #pragma unroll
    for (int r = 0; r < 4; ++r) { int oc = mf * 16 + 4 * g + r; b3v[r] = b3[oc]; w4v[r] = w4[oc]; }

    for (int nf = 0; nf < 3; ++nf) {
        int xl = nf * 16 + ln;
        f32x4 acc0 = {0.f,0.f,0.f,0.f}, acc1 = acc0;
        #pragma unroll
        for (int ks = 0; ks < 18; ++ks) {
            int tap = ks >> 1, icc = ks & 1;
            int dy = tap / 3, dx = tap - (tap / 3) * 3;
            int cc = xl + dx;
            int slot = (icc * 4 + g + cc) & 7;
            bf16x8 bfr = *(const bf16x8*)((const char*)tile + (size_t)(dy * 50 + cc) * 128 + slot * 16);
            if (ks & 1) acc1 = __builtin_amdgcn_mfma_f32_16x16x32_bf16(wf[ks], bfr, acc1, 0, 0, 0);
            else        acc0 = __builtin_amdgcn_mfma_f32_16x16x32_bf16(wf[ks], bfr, acc0, 0, 0, 0);
        }
        int xg = x0 + xl;
        float s4 = 0.f;
        #pragma unroll
        for (int r = 0; r < 4; ++r) {
            int oc = mf * 16 + 4 * g + r;
            float v = fmaxf(acc0[r] + acc1[r] + b3v[r], 0.f);
            out0[(size_t)oc * HW2 + y * 192 + xg] = v;
            s4 += v * w4v[r];
        }
        atomicAdd(&ps[xl], s4);
    }
    __syncthreads();
    if (tid < 48) {
        int xg = x0 + tid;
        out1[y * 192 + xg] = ps[tid] + b4[0];
        int ym = y % 48, xm = xg % 48;
        pm[y * 192 + xg] = ((ym == 0) | (ym == 47) | (xm == 0) | (xm == 47)) ? 0.6f : 1.0f;
    }
}

extern "C" void kernel_launch(void* const* d_in, const int* in_sizes, int n_in,
                              void* d_out, int out_size, void* d_ws, size_t ws_size,
                              hipStream_t stream)
{
    const float* x   = (const float*)d_in[0];
    const float* ref = (const float*)d_in[1];
    const float* unc = (const float*)d_in[2];
    const float* ipw = (const float*)d_in[3];
    const float* ipb = (const float*)d_in[4];
    const float* opw = (const float*)d_in[5];
    const float* opb = (const float*)d_in[6];
    const float* w1  = (const float*)d_in[7];
    const float* b1  = (const float*)d_in[8];
    const float* w3  = (const float*)d_in[9];
    const float* b3  = (const float*)d_in[10];
    const float* w4  = (const float*)d_in[11];
    const float* b4  = (const float*)d_in[12];

    char* ws = (char*)d_ws;
    u16_t* Qb    = (u16_t*)(ws);                  // 4,718,592
    u16_t* Kb    = (u16_t*)(ws + 4718592);        // 4,718,592
    u16_t* Vtb   = (u16_t*)(ws + 9437184);        // 4,718,592
    float* Ufp   = (float*)(ws + 14155776);       // 147,456
    float* meanV = (float*)(ws + 14303232);       // 4,096
    float* Wc    = (float*)(ws + 14307328);       // 16,384
    float* bc    = (float*)(ws + 14323712);       // 256
    u16_t* Wpk   = (u16_t*)(ws + 14323968);       // 73,728
    u16_t* Oatt  = (u16_t*)(ws + 14397696);       // 4,718,592
    u16_t* refd  = (u16_t*)(ws + 19116288);       // 4,718,592  (total 23,834,880 B)

    float* out0 = (float*)d_out;                  // r3: [1,64,192,192]
    float* out1 = out0 + 2359296;                 // out: [1,1,192,192]
    float* pmap = out0 + 2396160;                 // partition_map

    proj_kernel   <<<1152, 256, 0, stream>>>(x, ref, unc, ipw, ipb, Qb, Kb, Vtb, Ufp);
    prepmv_kernel <<<101,  256, 0, stream>>>(opw, opb, w1, b1, w3, Vtb, Wc, bc, Wpk, meanV);
    attn_kernel   <<<576,  256, 0, stream>>>(Qb, Kb, Vtb, Ufp, meanV, Oatt);
    refined_kernel<<<576,  256, 0, stream>>>(x, Oatt, Wc, bc, refd);
    conv_kernel   <<<768,  256, 0, stream>>>(refd, Wpk, b3, w4, b4, out0, out1, pmap);
}